// Round 1
// baseline (1053.569 us; speedup 1.0000x reference)
//
#include <hip/hip_runtime.h>
#include <math.h>

// Problem constants
#define DIMD 512
#define QS 64
#define QT 16
#define KS 256
#define KT 16
#define WIN 4
#define BATCH 8
#define RANK 32
#define NQ (QS*QT)          // 1024 q tokens per batch
#define NK (KS*KT)          // 4096 kv tokens per batch
#define MQ (BATCH*NQ)       // 8192 q rows
#define MK (BATCH*NK)       // 32768 kv rows

// ---------------------------------------------------------------------------
// FiLM conditioning: h = silu(ctx0@Wc0 + bc0 + ctx1@Wc1 + bc1)   [8,512]
// ---------------------------------------------------------------------------
__global__ __launch_bounds__(256) void film_h_kernel(
    const float* __restrict__ ctx0, const float* __restrict__ ctx1,
    const float* __restrict__ Wc0, const float* __restrict__ bc0,
    const float* __restrict__ Wc1, const float* __restrict__ bc1,
    float* __restrict__ h)
{
    int t = blockIdx.x * 256 + threadIdx.x;     // 0..4095
    int b = t >> 9, d = t & 511;
    float acc = bc0[d] + bc1[d];
    const float* c0 = ctx0 + b * DIMD;
    const float* c1 = ctx1 + b * DIMD;
    for (int i = 0; i < DIMD; i++) {
        acc = fmaf(c0[i], Wc0[i * DIMD + d], acc);
        acc = fmaf(c1[i], Wc1[i * DIMD + d], acc);
    }
    h[t] = acc / (1.f + expf(-acc));            // silu
}

// gamma,beta = split(h @ Wf + bf)  Wf: [512, 1024]
__global__ __launch_bounds__(256) void film_gb_kernel(
    const float* __restrict__ h, const float* __restrict__ Wf,
    const float* __restrict__ bfv,
    float* __restrict__ gamma, float* __restrict__ beta)
{
    int t = blockIdx.x * 256 + threadIdx.x;     // 0..4095
    int b = t >> 9, d = t & 511;
    float ga = bfv[d], be = bfv[DIMD + d];
    const float* hb = h + b * DIMD;
    for (int i = 0; i < DIMD; i++) {
        float hv = hb[i];
        ga = fmaf(hv, Wf[i * 2 * DIMD + d], ga);
        be = fmaf(hv, Wf[i * 2 * DIMD + DIMD + d], be);
    }
    gamma[t] = ga;
    beta[t] = be;
}

// ---------------------------------------------------------------------------
// Per-row layernorm stats: mu, rstd over 512 elements. One block per row.
// ---------------------------------------------------------------------------
__global__ __launch_bounds__(256) void row_stats_kernel(
    const float* __restrict__ X, float* __restrict__ mu, float* __restrict__ rstd)
{
    int row = blockIdx.x;
    const float* x = X + (long)row * DIMD;
    int t = threadIdx.x;
    float a = x[t], b = x[t + 256];
    float s = a + b, ss = a * a + b * b;
    #pragma unroll
    for (int o = 32; o >= 1; o >>= 1) {
        s  += __shfl_down(s, o);
        ss += __shfl_down(ss, o);
    }
    __shared__ float ls[4], lss[4];
    if ((t & 63) == 0) { ls[t >> 6] = s; lss[t >> 6] = ss; }
    __syncthreads();
    if (t == 0) {
        float S = ls[0] + ls[1] + ls[2] + ls[3];
        float SS = lss[0] + lss[1] + lss[2] + lss[3];
        float m = S * (1.f / DIMD);
        float var = SS * (1.f / DIMD) - m * m;
        mu[row] = m;
        rstd[row] = rsqrtf(var + 1e-5f);
    }
}

// ---------------------------------------------------------------------------
// Fused-LN GEMM: C[M,512] = f(A) @ W + bias
//   MODE 0: f = identity            (ctx @ Wo)
//   MODE 1: f = LN(A)*g+b           (source -> k_p, v_p)
//   MODE 2: f = (LN(A)*g+b)*(1+gamma[b])+beta[b]   (query -> q_p)
// 128x128 tile, BK=16, 256 threads, 8x8 micro-tile split as 2x2 quadrants of
// 4x4 for conflict-free float4 LDS reads.
// ---------------------------------------------------------------------------
template<int MODE>
__global__ __launch_bounds__(256) void gemm_ln_kernel(
    const float* __restrict__ A, const float* __restrict__ W,
    const float* __restrict__ bias, float* __restrict__ C,
    const float* __restrict__ mu, const float* __restrict__ rstd,
    const float* __restrict__ lng, const float* __restrict__ lnb,
    const float* __restrict__ gamma, const float* __restrict__ beta)
{
    __shared__ float As[16][132];   // [k][m], padded
    __shared__ float Bs[16][132];   // [k][n], padded
    int t = threadIdx.x;
    int n0 = blockIdx.x * 128;
    int m0 = blockIdx.y * 128;
    int tm = t >> 4, tn = t & 15;

    float acc[8][8] = {};

    for (int k0 = 0; k0 < DIMD; k0 += 16) {
        __syncthreads();
        // stage A tile: 128 rows x 16 cols
        #pragma unroll
        for (int u = 0; u < 2; u++) {
            int idx = t + u * 256;            // 0..511
            int r = idx >> 2;                 // 0..127
            int c4 = (idx & 3) << 2;          // 0,4,8,12
            int grow = m0 + r;
            float4 v = *(const float4*)&A[(long)grow * DIMD + k0 + c4];
            if constexpr (MODE != 0) {
                float m_ = mu[grow], rs_ = rstd[grow];
                float4 g4 = *(const float4*)&lng[k0 + c4];
                float4 b4 = *(const float4*)&lnb[k0 + c4];
                v.x = (v.x - m_) * rs_ * g4.x + b4.x;
                v.y = (v.y - m_) * rs_ * g4.y + b4.y;
                v.z = (v.z - m_) * rs_ * g4.z + b4.z;
                v.w = (v.w - m_) * rs_ * g4.w + b4.w;
                if constexpr (MODE == 2) {
                    int bt = grow >> 10;      // row / 1024
                    float4 gm = *(const float4*)&gamma[bt * DIMD + k0 + c4];
                    float4 be = *(const float4*)&beta[bt * DIMD + k0 + c4];
                    v.x = v.x * (1.f + gm.x) + be.x;
                    v.y = v.y * (1.f + gm.y) + be.y;
                    v.z = v.z * (1.f + gm.z) + be.z;
                    v.w = v.w * (1.f + gm.w) + be.w;
                }
            }
            As[c4 + 0][r] = v.x;
            As[c4 + 1][r] = v.y;
            As[c4 + 2][r] = v.z;
            As[c4 + 3][r] = v.w;
        }
        // stage B tile: 16 rows x 128 cols
        #pragma unroll
        for (int u = 0; u < 2; u++) {
            int idx = t + u * 256;
            int r = idx >> 5;                 // 0..15
            int c4 = (idx & 31) << 2;         // 0..124
            float4 v = *(const float4*)&W[(long)(k0 + r) * DIMD + n0 + c4];
            *(float4*)&Bs[r][c4] = v;
        }
        __syncthreads();
        #pragma unroll
        for (int kk = 0; kk < 16; kk++) {
            float4 a0 = *(const float4*)&As[kk][tm * 4];
            float4 a1 = *(const float4*)&As[kk][64 + tm * 4];
            float4 b0 = *(const float4*)&Bs[kk][tn * 4];
            float4 b1 = *(const float4*)&Bs[kk][64 + tn * 4];
            float ar[8] = {a0.x, a0.y, a0.z, a0.w, a1.x, a1.y, a1.z, a1.w};
            float br[8] = {b0.x, b0.y, b0.z, b0.w, b1.x, b1.y, b1.z, b1.w};
            #pragma unroll
            for (int i = 0; i < 8; i++)
                #pragma unroll
                for (int j = 0; j < 8; j++)
                    acc[i][j] = fmaf(ar[i], br[j], acc[i][j]);
        }
    }
    // epilogue
    #pragma unroll
    for (int i = 0; i < 8; i++) {
        int row = m0 + ((i < 4) ? (tm * 4 + i) : (64 + tm * 4 + (i - 4)));
        #pragma unroll
        for (int jq = 0; jq < 2; jq++) {
            int col = n0 + jq * 64 + tn * 4;
            float4 bb = *(const float4*)&bias[col];
            float4 o;
            o.x = acc[i][jq * 4 + 0] + bb.x;
            o.y = acc[i][jq * 4 + 1] + bb.y;
            o.z = acc[i][jq * 4 + 2] + bb.z;
            o.w = acc[i][jq * 4 + 3] + bb.w;
            *(float4*)&C[(long)row * DIMD + col] = o;
        }
    }
}

// ---------------------------------------------------------------------------
// Gate GEMM: G[M,32] = P[M,512] @ Wg[512,32]. Block: 8 rows x 32 cols.
// ---------------------------------------------------------------------------
__global__ __launch_bounds__(256) void gate_gemm_kernel(
    const float* __restrict__ P, const float* __restrict__ Wg, float* __restrict__ G)
{
    __shared__ float Pl[8 * DIMD];
    int t = threadIdx.x;
    long r0 = (long)blockIdx.x * 8;
    const float4* src = (const float4*)(P + r0 * DIMD);
    float4* dst = (float4*)Pl;
    for (int i = t; i < 8 * DIMD / 4; i += 256) dst[i] = src[i];
    __syncthreads();
    int r = t >> 5, c = t & 31;
    const float* pr = Pl + r * DIMD;
    float acc = 0.f;
    #pragma unroll 4
    for (int i = 0; i < DIMD; i++) acc = fmaf(pr[i], Wg[i * RANK + c], acc);
    G[(r0 + r) * RANK + c] = acc;
}

// ---------------------------------------------------------------------------
// Fused local attention. One block per (b, q-step): 16 q rows vs <=144 kv rows.
// scores = (q.k)*scale + log(sigmoid(gq.gk/sqrt(32)) + 1e-6); softmax; ctx=attn@v
// ---------------------------------------------------------------------------
__global__ __launch_bounds__(256) void attn_kernel(
    const float* __restrict__ q_p, const float* __restrict__ k_p,
    const float* __restrict__ v_p, const float* __restrict__ gq_all,
    const float* __restrict__ gk_all, float* __restrict__ ctx)
{
    __shared__ float kv_lds[16][516];   // k rows (phase B), v rows (phase D)
    __shared__ float sc[16][144];
    __shared__ float gq[16][36];
    __shared__ float gk[16][36];

    int blk = blockIdx.x;
    int b = blk >> 6;          // 0..7
    int qs = blk & 63;         // 0..63
    int center = (int)(qs * (255.0 / 63.0) + 0.5);
    int lo = center - WIN; if (lo < 0) lo = 0;
    int hi = center + WIN; if (hi > KS - 1) hi = KS - 1;
    int nst = hi - lo + 1;
    int nkv = nst * 16;
    int rowq0 = b * NQ + qs * 16;
    int rowk0 = b * NK + lo * 16;

    int t = threadIdx.x;
    int qi = t >> 4, ki = t & 15;

    // load gate_q tile
    for (int i = t; i < 16 * 8; i += 256) {
        int r = i >> 3, c4 = (i & 7) << 2;
        *(float4*)&gq[r][c4] = *(const float4*)&gq_all[(rowq0 + r) * RANK + c4];
    }

    const float scale = 0.044194173824159216f;   // 512^-0.5
    const float giscale = 0.17677669529663687f;  // 32^-0.5
    const float* qrow = q_p + (long)(rowq0 + qi) * DIMD;

    // ---- phase B: scores ----
    for (int st = 0; st < nst; st++) {
        __syncthreads();
        int rk = rowk0 + st * 16;
        for (int i = t; i < 16 * 128; i += 256) {
            int r = i >> 7, c4 = (i & 127) << 2;
            *(float4*)&kv_lds[r][c4] = *(const float4*)&k_p[(long)(rk + r) * DIMD + c4];
        }
        for (int i = t; i < 16 * 8; i += 256) {
            int r = i >> 3, c4 = (i & 7) << 2;
            *(float4*)&gk[r][c4] = *(const float4*)&gk_all[(rk + r) * RANK + c4];
        }
        __syncthreads();
        float acc = 0.f;
        #pragma unroll 8
        for (int i = 0; i < DIMD; i += 4) {
            float4 qa = *(const float4*)&qrow[i];
            float4 ka = *(const float4*)&kv_lds[ki][i];
            acc = fmaf(qa.x, ka.x, acc);
            acc = fmaf(qa.y, ka.y, acc);
            acc = fmaf(qa.z, ka.z, acc);
            acc = fmaf(qa.w, ka.w, acc);
        }
        float g = 0.f;
        #pragma unroll
        for (int i = 0; i < RANK; i += 4) {
            float4 qa = *(const float4*)&gq[qi][i];
            float4 ka = *(const float4*)&gk[ki][i];
            g = fmaf(qa.x, ka.x, g);
            g = fmaf(qa.y, ka.y, g);
            g = fmaf(qa.z, ka.z, g);
            g = fmaf(qa.w, ka.w, g);
        }
        float sig = 1.f / (1.f + expf(-g * giscale));
        float gbias = logf(sig + 1e-6f);
        sc[qi][st * 16 + ki] = acc * scale + gbias;
    }
    __syncthreads();

    // ---- phase C: softmax per q row; lanes (qi, ki) cover row qi ----
    float m = -1e30f;
    for (int j = ki; j < nkv; j += 16) m = fmaxf(m, sc[qi][j]);
    #pragma unroll
    for (int o = 8; o >= 1; o >>= 1) m = fmaxf(m, __shfl_xor(m, o, 16));
    float s = 0.f;
    for (int j = ki; j < nkv; j += 16) {
        float e = expf(sc[qi][j] - m);
        sc[qi][j] = e;
        s += e;
    }
    #pragma unroll
    for (int o = 8; o >= 1; o >>= 1) s += __shfl_xor(s, o, 16);
    float inv = 1.f / s;

    // ---- phase D: ctx = attn @ v ----
    float acc2[8][4] = {};
    for (int st = 0; st < nst; st++) {
        __syncthreads();
        int rk = rowk0 + st * 16;
        for (int i = t; i < 16 * 128; i += 256) {
            int r = i >> 7, c4 = (i & 127) << 2;
            *(float4*)&kv_lds[r][c4] = *(const float4*)&v_p[(long)(rk + r) * DIMD + c4];
        }
        __syncthreads();
        #pragma unroll
        for (int j = 0; j < 16; j++) {
            float a = sc[qi][st * 16 + j] * inv;
            int base = ki << 2;
            #pragma unroll
            for (int ch = 0; ch < 8; ch++) {
                float4 vv = *(const float4*)&kv_lds[j][ch * 64 + base];
                acc2[ch][0] = fmaf(a, vv.x, acc2[ch][0]);
                acc2[ch][1] = fmaf(a, vv.y, acc2[ch][1]);
                acc2[ch][2] = fmaf(a, vv.z, acc2[ch][2]);
                acc2[ch][3] = fmaf(a, vv.w, acc2[ch][3]);
            }
        }
    }
    #pragma unroll
    for (int ch = 0; ch < 8; ch++) {
        float4 o;
        o.x = acc2[ch][0]; o.y = acc2[ch][1]; o.z = acc2[ch][2]; o.w = acc2[ch][3];
        *(float4*)&ctx[(long)(rowq0 + qi) * DIMD + ch * 64 + (ki << 2)] = o;
    }
}

// ---------------------------------------------------------------------------
extern "C" void kernel_launch(void* const* d_in, const int* in_sizes, int n_in,
                              void* d_out, int out_size, void* d_ws, size_t ws_size,
                              hipStream_t stream) {
    const float* query  = (const float*)d_in[0];
    const float* source = (const float*)d_in[1];
    const float* ctx0   = (const float*)d_in[2];
    const float* ctx1   = (const float*)d_in[3];
    // d_in[4] = mask: structurally known (local window, 0 inside), unused
    const float* qn_g  = (const float*)d_in[5];
    const float* qn_b  = (const float*)d_in[6];
    const float* kvn_g = (const float*)d_in[7];
    const float* kvn_b = (const float*)d_in[8];
    const float* Wq = (const float*)d_in[9];   const float* bq = (const float*)d_in[10];
    const float* Wk = (const float*)d_in[11];  const float* bk = (const float*)d_in[12];
    const float* Wv = (const float*)d_in[13];  const float* bv = (const float*)d_in[14];
    const float* Wo = (const float*)d_in[15];  const float* bo = (const float*)d_in[16];
    const float* Wgq = (const float*)d_in[17];
    const float* Wgk = (const float*)d_in[18];
    const float* Wc0 = (const float*)d_in[19]; const float* bc0 = (const float*)d_in[20];
    const float* Wc1 = (const float*)d_in[21]; const float* bc1 = (const float*)d_in[22];
    const float* Wf  = (const float*)d_in[23]; const float* bfv = (const float*)d_in[24];

    float* ws = (float*)d_ws;
    float* h      = ws;                        // 4096
    float* gamma  = h + 4096;                  // 4096
    float* beta   = gamma + 4096;              // 4096
    float* mu_q   = beta + 4096;               // 8192
    float* rs_q   = mu_q + 8192;               // 8192
    float* mu_s   = rs_q + 8192;               // 32768
    float* rs_s   = mu_s + 32768;              // 32768
    float* q_p    = rs_s + 32768;              // 8192*512
    float* k_p    = q_p + (long)MQ * DIMD;     // 32768*512
    float* v_p    = k_p + (long)MK * DIMD;     // 32768*512
    float* gate_q = v_p + (long)MK * DIMD;     // 8192*32
    float* gate_k = gate_q + (long)MQ * RANK;  // 32768*32
    float* ctxbuf = gate_k + (long)MK * RANK;  // 8192*512
    float* out = (float*)d_out;

    film_h_kernel<<<16, 256, 0, stream>>>(ctx0, ctx1, Wc0, bc0, Wc1, bc1, h);
    film_gb_kernel<<<16, 256, 0, stream>>>(h, Wf, bfv, gamma, beta);
    row_stats_kernel<<<MQ, 256, 0, stream>>>(query, mu_q, rs_q);
    row_stats_kernel<<<MK, 256, 0, stream>>>(source, mu_s, rs_s);

    gemm_ln_kernel<2><<<dim3(4, MQ / 128), 256, 0, stream>>>(
        query, Wq, bq, q_p, mu_q, rs_q, qn_g, qn_b, gamma, beta);
    gemm_ln_kernel<1><<<dim3(4, MK / 128), 256, 0, stream>>>(
        source, Wk, bk, k_p, mu_s, rs_s, kvn_g, kvn_b, nullptr, nullptr);
    gemm_ln_kernel<1><<<dim3(4, MK / 128), 256, 0, stream>>>(
        source, Wv, bv, v_p, mu_s, rs_s, kvn_g, kvn_b, nullptr, nullptr);

    gate_gemm_kernel<<<MQ / 8, 256, 0, stream>>>(q_p, Wgq, gate_q);
    gate_gemm_kernel<<<MK / 8, 256, 0, stream>>>(k_p, Wgk, gate_k);

    attn_kernel<<<BATCH * QS, 256, 0, stream>>>(q_p, k_p, v_p, gate_q, gate_k, ctxbuf);

    gemm_ln_kernel<0><<<dim3(4, MQ / 128), 256, 0, stream>>>(
        ctxbuf, Wo, bo, out, nullptr, nullptr, nullptr, nullptr, nullptr, nullptr);
}

// Round 2
// 627.955 us; speedup vs baseline: 1.6778x; 1.6778x over previous
//
#include <hip/hip_runtime.h>
#include <math.h>

// Problem constants
#define DIMD 512
#define QS 64
#define KS 256
#define WIN 4
#define BATCH 8
#define RANK 32
#define NQ 1024             // q tokens per batch
#define NK 4096             // kv tokens per batch
#define MQ (BATCH*NQ)       // 8192 q rows
#define MK (BATCH*NK)       // 32768 kv rows

typedef unsigned short u16;
typedef __attribute__((ext_vector_type(8))) short bf16x8;  // MFMA A/B frag (8 bf16)
typedef __attribute__((ext_vector_type(4))) float f32x4;   // MFMA C/D frag
typedef __attribute__((ext_vector_type(4))) unsigned short u16x4;

__device__ inline u16 f2bf(float x) {
    union { float f; unsigned int u; } v; v.f = x;
    unsigned int r = v.u + 0x7FFF + ((v.u >> 16) & 1);
    return (u16)(r >> 16);
}

// ---------------------------------------------------------------------------
// FiLM conditioning: h = silu(ctx0@Wc0 + bc0 + ctx1@Wc1 + bc1)   [8,512]
// ---------------------------------------------------------------------------
__global__ __launch_bounds__(256) void film_h_kernel(
    const float* __restrict__ ctx0, const float* __restrict__ ctx1,
    const float* __restrict__ Wc0, const float* __restrict__ bc0,
    const float* __restrict__ Wc1, const float* __restrict__ bc1,
    float* __restrict__ h)
{
    int t = blockIdx.x * 256 + threadIdx.x;     // 0..4095
    int b = t >> 9, d = t & 511;
    float acc = bc0[d] + bc1[d];
    const float* c0 = ctx0 + b * DIMD;
    const float* c1 = ctx1 + b * DIMD;
    for (int i = 0; i < DIMD; i++) {
        acc = fmaf(c0[i], Wc0[i * DIMD + d], acc);
        acc = fmaf(c1[i], Wc1[i * DIMD + d], acc);
    }
    h[t] = acc / (1.f + expf(-acc));            // silu
}

// gamma,beta = split(h @ Wf + bf)  Wf: [512, 1024]
__global__ __launch_bounds__(256) void film_gb_kernel(
    const float* __restrict__ h, const float* __restrict__ Wf,
    const float* __restrict__ bfv,
    float* __restrict__ gamma, float* __restrict__ beta)
{
    int t = blockIdx.x * 256 + threadIdx.x;     // 0..4095
    int b = t >> 9, d = t & 511;
    float ga = bfv[d], be = bfv[DIMD + d];
    const float* hb = h + b * DIMD;
    for (int i = 0; i < DIMD; i++) {
        float hv = hb[i];
        ga = fmaf(hv, Wf[i * 2 * DIMD + d], ga);
        be = fmaf(hv, Wf[i * 2 * DIMD + DIMD + d], be);
    }
    gamma[t] = ga;
    beta[t] = be;
}

// ---------------------------------------------------------------------------
// Fused LN (+FiLM) -> bf16. One block per row.
// FILM=0: out = LN(x)*g+b ;  FILM=1: out = (LN(x)*g+b)*(1+gamma[bt])+beta[bt]
// ---------------------------------------------------------------------------
template<int FILM>
__global__ __launch_bounds__(256) void norm_bf16_kernel(
    const float* __restrict__ X, const float* __restrict__ g, const float* __restrict__ bb,
    const float* __restrict__ gamma, const float* __restrict__ beta,
    u16* __restrict__ out)
{
    int row = blockIdx.x;
    const float* x = X + (long)row * DIMD;
    int t = threadIdx.x;
    float a0 = x[t], a1 = x[t + 256];
    float s = a0 + a1, ss = a0 * a0 + a1 * a1;
    #pragma unroll
    for (int o = 32; o >= 1; o >>= 1) {
        s  += __shfl_down(s, o);
        ss += __shfl_down(ss, o);
    }
    __shared__ float ls[4], lss[4];
    if ((t & 63) == 0) { ls[t >> 6] = s; lss[t >> 6] = ss; }
    __syncthreads();
    float S = ls[0] + ls[1] + ls[2] + ls[3];
    float SS = lss[0] + lss[1] + lss[2] + lss[3];
    float mu = S * (1.f / DIMD);
    float var = SS * (1.f / DIMD) - mu * mu;
    float rs = rsqrtf(var + 1e-5f);
    float v0 = (a0 - mu) * rs * g[t] + bb[t];
    float v1 = (a1 - mu) * rs * g[t + 256] + bb[t + 256];
    if (FILM) {
        int bt = row >> 10;    // 1024 q rows per batch
        v0 = v0 * (1.f + gamma[bt * DIMD + t]) + beta[bt * DIMD + t];
        v1 = v1 * (1.f + gamma[bt * DIMD + t + 256]) + beta[bt * DIMD + t + 256];
    }
    out[(long)row * DIMD + t] = f2bf(v0);
    out[(long)row * DIMD + t + 256] = f2bf(v1);
}

// ---------------------------------------------------------------------------
// Transpose fp32 W[512][ncols] -> bf16 dst rows: dst[dst_row_off + n][k] = W[k][n]
// Grid: (ncols/32, 512/32), block 256 (32x8).
// ---------------------------------------------------------------------------
__global__ __launch_bounds__(256) void transpose_bf16_kernel(
    const float* __restrict__ src, u16* __restrict__ dst, int ncols, int dst_row_off)
{
    __shared__ float tile[32][33];
    int t = threadIdx.x;
    int tx = t & 31, ty = t >> 5;           // ty 0..7
    int bx = blockIdx.x * 32;               // n
    int by = blockIdx.y * 32;               // k
    #pragma unroll
    for (int i = 0; i < 4; i++)
        tile[ty + i * 8][tx] = src[(long)(by + ty + i * 8) * ncols + bx + tx];
    __syncthreads();
    #pragma unroll
    for (int i = 0; i < 4; i++)
        dst[(long)(dst_row_off + bx + ty + i * 8) * DIMD + by + tx] = f2bf(tile[tx][ty + i * 8]);
}

// ---------------------------------------------------------------------------
// Fused gate weight: dst[dst_row_off + r][k] = sum_j W[k][j] * Wg[j][r]  (r<32)
// Grid: 64 blocks x 256 threads.
// ---------------------------------------------------------------------------
__global__ __launch_bounds__(256) void gatefuse_kernel(
    const float* __restrict__ W, const float* __restrict__ Wg,
    u16* __restrict__ dst, int dst_row_off)
{
    int idx = blockIdx.x * 256 + threadIdx.x;   // 0..16383
    int r = idx & 31, k = idx >> 5;
    float acc = 0.f;
    #pragma unroll 4
    for (int j = 0; j < DIMD; j++) acc = fmaf(W[k * DIMD + j], Wg[j * RANK + r], acc);
    dst[(long)(dst_row_off + r) * DIMD + k] = f2bf(acc);
}

// biascat for kv: [bk(512) | bv(512) | bk@Wgk(32)], grid 5x256 (=1280 >= 1056)
__global__ __launch_bounds__(256) void biascat3_kernel(
    const float* __restrict__ b0, const float* __restrict__ b1,
    const float* __restrict__ Wg, float* __restrict__ dst)
{
    int t = blockIdx.x * 256 + threadIdx.x;
    if (t < 512) dst[t] = b0[t];
    else if (t < 1024) dst[t] = b1[t - 512];
    else if (t < 1056) {
        int r = t - 1024;
        float a = 0.f;
        for (int j = 0; j < DIMD; j++) a = fmaf(b0[j], Wg[j * RANK + r], a);
        dst[t] = a;
    }
}

// biascat for q: [bq(512) | bq@Wgq(32)], grid 3x256
__global__ __launch_bounds__(256) void biascat2_kernel(
    const float* __restrict__ b0, const float* __restrict__ Wg, float* __restrict__ dst)
{
    int t = blockIdx.x * 256 + threadIdx.x;
    if (t < 512) dst[t] = b0[t];
    else if (t < 544) {
        int r = t - 512;
        float a = 0.f;
        for (int j = 0; j < DIMD; j++) a = fmaf(b0[j], Wg[j * RANK + r], a);
        dst[t] = a;
    }
}

// ---------------------------------------------------------------------------
// bf16 MFMA GEMM:  C = A[M][512]bf16 @ Bt[N][512]bf16^T + biascat
// 128x128 tile, BK=32, 256 threads = 4 waves, wave = 64x64 quadrant of 4x4
// 16x16x32 MFMAs. Output routed by column section:
//   NSEC=1: all 512 cols -> C0
//   NSEC=2: [0,512)->C0, [512,544)->Cg (width 32)
//   NSEC=3: [0,512)->C0, [512,1024)->C1, [1024,1056)->Cg
// ---------------------------------------------------------------------------
template<int NSEC>
__global__ __launch_bounds__(256) void gemm_mfma_kernel(
    const u16* __restrict__ A, const u16* __restrict__ Bt,
    const float* __restrict__ biascat,
    float* __restrict__ C0, float* __restrict__ C1, float* __restrict__ Cg,
    int Nvalid)
{
    __shared__ u16 As[128 * 32];
    __shared__ u16 Bs[128 * 32];
    int t = threadIdx.x;
    int wave = t >> 6, lane = t & 63;
    int m0 = blockIdx.y * 128;
    int n0 = blockIdx.x * 128;
    int mhalf = (wave >> 1) * 64, nhalf = (wave & 1) * 64;
    int lm = lane & 15, quad = lane >> 4;

    f32x4 acc[4][4];
    #pragma unroll
    for (int i = 0; i < 4; i++)
        #pragma unroll
        for (int j = 0; j < 4; j++)
            acc[i][j] = (f32x4){0.f, 0.f, 0.f, 0.f};

    for (int k0 = 0; k0 < DIMD; k0 += 32) {
        __syncthreads();
        // stage A and B tiles: 128 rows x 32 bf16 each (linear [row][k] layout)
        #pragma unroll
        for (int u = 0; u < 2; u++) {
            int L = t + u * 256;              // 0..511
            int r = L >> 2;                   // row 0..127
            int cb = (L & 3) << 3;            // bf16 col 0,8,16,24
            *(int4*)&As[L * 8] = *(const int4*)&A[(long)(m0 + r) * DIMD + k0 + cb];
            *(int4*)&Bs[L * 8] = *(const int4*)&Bt[(long)(n0 + r) * DIMD + k0 + cb];
        }
        __syncthreads();
        bf16x8 af[4], bfr[4];
        #pragma unroll
        for (int i = 0; i < 4; i++) {
            af[i]  = *(const bf16x8*)&As[(mhalf + i * 16 + lm) * 32 + quad * 8];
            bfr[i] = *(const bf16x8*)&Bs[(nhalf + i * 16 + lm) * 32 + quad * 8];
        }
        #pragma unroll
        for (int i = 0; i < 4; i++)
            #pragma unroll
            for (int j = 0; j < 4; j++)
                acc[i][j] = __builtin_amdgcn_mfma_f32_16x16x32_bf16(af[i], bfr[j], acc[i][j], 0, 0, 0);
    }

    // epilogue: C/D layout col=lane&15, row=quad*4+reg
    #pragma unroll
    for (int j = 0; j < 4; j++) {
        int col = n0 + nhalf + j * 16 + lm;
        if (col >= Nvalid) continue;
        float bias = biascat[col];
        float* dst; int cw, ccol;
        if (NSEC == 1) { dst = C0; cw = 512; ccol = col; }
        else if (NSEC == 2) {
            if (col < 512) { dst = C0; cw = 512; ccol = col; }
            else           { dst = Cg; cw = 32;  ccol = col - 512; }
        } else {
            if (col < 512)       { dst = C0; cw = 512; ccol = col; }
            else if (col < 1024) { dst = C1; cw = 512; ccol = col - 512; }
            else                 { dst = Cg; cw = 32;  ccol = col - 1024; }
        }
        #pragma unroll
        for (int i = 0; i < 4; i++) {
            int row0 = m0 + mhalf + i * 16 + quad * 4;
            #pragma unroll
            for (int r = 0; r < 4; r++)
                dst[(long)(row0 + r) * cw + ccol] = acc[i][j][r] + bias;
        }
    }
}

// ---------------------------------------------------------------------------
// Fused local attention (fp32), writes ctx as bf16.
// One block per (b, q-step): 16 q rows vs <=144 kv rows.
// ---------------------------------------------------------------------------
__global__ __launch_bounds__(256) void attn_kernel(
    const float* __restrict__ q_p, const float* __restrict__ k_p,
    const float* __restrict__ v_p, const float* __restrict__ gq_all,
    const float* __restrict__ gk_all, u16* __restrict__ ctx)
{
    __shared__ float kv_lds[16][516];
    __shared__ float sc[16][144];
    __shared__ float gq[16][36];
    __shared__ float gk[16][36];

    int blk = blockIdx.x;
    int b = blk >> 6;
    int qs = blk & 63;
    int center = (int)(qs * (255.0 / 63.0) + 0.5);
    int lo = center - WIN; if (lo < 0) lo = 0;
    int hi = center + WIN; if (hi > KS - 1) hi = KS - 1;
    int nst = hi - lo + 1;
    int nkv = nst * 16;
    int rowq0 = b * NQ + qs * 16;
    int rowk0 = b * NK + lo * 16;

    int t = threadIdx.x;
    int qi = t >> 4, ki = t & 15;

    for (int i = t; i < 16 * 8; i += 256) {
        int r = i >> 3, c4 = (i & 7) << 2;
        *(float4*)&gq[r][c4] = *(const float4*)&gq_all[(rowq0 + r) * RANK + c4];
    }

    const float scale = 0.044194173824159216f;   // 512^-0.5
    const float giscale = 0.17677669529663687f;  // 32^-0.5
    const float* qrow = q_p + (long)(rowq0 + qi) * DIMD;

    // ---- scores ----
    for (int st = 0; st < nst; st++) {
        __syncthreads();
        int rk = rowk0 + st * 16;
        for (int i = t; i < 16 * 128; i += 256) {
            int r = i >> 7, c4 = (i & 127) << 2;
            *(float4*)&kv_lds[r][c4] = *(const float4*)&k_p[(long)(rk + r) * DIMD + c4];
        }
        for (int i = t; i < 16 * 8; i += 256) {
            int r = i >> 3, c4 = (i & 7) << 2;
            *(float4*)&gk[r][c4] = *(const float4*)&gk_all[(rk + r) * RANK + c4];
        }
        __syncthreads();
        float acc = 0.f;
        #pragma unroll 8
        for (int i = 0; i < DIMD; i += 4) {
            float4 qa = *(const float4*)&qrow[i];
            float4 ka = *(const float4*)&kv_lds[ki][i];
            acc = fmaf(qa.x, ka.x, acc);
            acc = fmaf(qa.y, ka.y, acc);
            acc = fmaf(qa.z, ka.z, acc);
            acc = fmaf(qa.w, ka.w, acc);
        }
        float g = 0.f;
        #pragma unroll
        for (int i = 0; i < RANK; i += 4) {
            float4 qa = *(const float4*)&gq[qi][i];
            float4 ka = *(const float4*)&gk[ki][i];
            g = fmaf(qa.x, ka.x, g);
            g = fmaf(qa.y, ka.y, g);
            g = fmaf(qa.z, ka.z, g);
            g = fmaf(qa.w, ka.w, g);
        }
        float sig = 1.f / (1.f + expf(-g * giscale));
        float gbias = logf(sig + 1e-6f);
        sc[qi][st * 16 + ki] = acc * scale + gbias;
    }
    __syncthreads();

    // ---- softmax per q row ----
    float m = -1e30f;
    for (int j = ki; j < nkv; j += 16) m = fmaxf(m, sc[qi][j]);
    #pragma unroll
    for (int o = 8; o >= 1; o >>= 1) m = fmaxf(m, __shfl_xor(m, o, 16));
    float s = 0.f;
    for (int j = ki; j < nkv; j += 16) {
        float e = expf(sc[qi][j] - m);
        sc[qi][j] = e;
        s += e;
    }
    #pragma unroll
    for (int o = 8; o >= 1; o >>= 1) s += __shfl_xor(s, o, 16);
    float inv = 1.f / s;

    // ---- ctx = attn @ v ----
    float acc2[8][4] = {};
    for (int st = 0; st < nst; st++) {
        __syncthreads();
        int rk = rowk0 + st * 16;
        for (int i = t; i < 16 * 128; i += 256) {
            int r = i >> 7, c4 = (i & 127) << 2;
            *(float4*)&kv_lds[r][c4] = *(const float4*)&v_p[(long)(rk + r) * DIMD + c4];
        }
        __syncthreads();
        #pragma unroll
        for (int j = 0; j < 16; j++) {
            float a = sc[qi][st * 16 + j] * inv;
            int base = ki << 2;
            #pragma unroll
            for (int ch = 0; ch < 8; ch++) {
                float4 vv = *(const float4*)&kv_lds[j][ch * 64 + base];
                acc2[ch][0] = fmaf(a, vv.x, acc2[ch][0]);
                acc2[ch][1] = fmaf(a, vv.y, acc2[ch][1]);
                acc2[ch][2] = fmaf(a, vv.z, acc2[ch][2]);
                acc2[ch][3] = fmaf(a, vv.w, acc2[ch][3]);
            }
        }
    }
    #pragma unroll
    for (int ch = 0; ch < 8; ch++) {
        u16x4 o;
        o.x = f2bf(acc2[ch][0]); o.y = f2bf(acc2[ch][1]);
        o.z = f2bf(acc2[ch][2]); o.w = f2bf(acc2[ch][3]);
        *(u16x4*)&ctx[(long)(rowq0 + qi) * DIMD + ch * 64 + (ki << 2)] = o;
    }
}

// ---------------------------------------------------------------------------
extern "C" void kernel_launch(void* const* d_in, const int* in_sizes, int n_in,
                              void* d_out, int out_size, void* d_ws, size_t ws_size,
                              hipStream_t stream) {
    const float* query  = (const float*)d_in[0];
    const float* source = (const float*)d_in[1];
    const float* ctx0   = (const float*)d_in[2];
    const float* ctx1   = (const float*)d_in[3];
    // d_in[4] = mask: structurally known (local window, 0 inside), unused
    const float* qn_g  = (const float*)d_in[5];
    const float* qn_b  = (const float*)d_in[6];
    const float* kvn_g = (const float*)d_in[7];
    const float* kvn_b = (const float*)d_in[8];
    const float* Wq = (const float*)d_in[9];   const float* bq = (const float*)d_in[10];
    const float* Wk = (const float*)d_in[11];  const float* bk = (const float*)d_in[12];
    const float* Wv = (const float*)d_in[13];  const float* bv = (const float*)d_in[14];
    const float* Wo = (const float*)d_in[15];  const float* bo = (const float*)d_in[16];
    const float* Wgq = (const float*)d_in[17];
    const float* Wgk = (const float*)d_in[18];
    const float* Wc0 = (const float*)d_in[19]; const float* bc0 = (const float*)d_in[20];
    const float* Wc1 = (const float*)d_in[21]; const float* bc1 = (const float*)d_in[22];
    const float* Wf  = (const float*)d_in[23]; const float* bfv = (const float*)d_in[24];

    // ---- workspace layout ----
    float* ws = (float*)d_ws;
    float* h      = ws;                         // 4096
    float* gamma  = h + 4096;                   // 4096
    float* beta   = gamma + 4096;               // 4096
    float* biaskv = beta + 4096;                // 1088
    float* biasq  = biaskv + 1088;              // 576  (total 13952 fl = 55808 B)
    float* k_p    = biasq + 576;                // 32768*512
    float* v_p    = k_p + (long)MK * DIMD;      // 32768*512
    float* q_p    = v_p + (long)MK * DIMD;      // 8192*512
    float* gate_k = q_p + (long)MQ * DIMD;      // 32768*32
    float* gate_q = gate_k + (long)MK * RANK;   // 8192*32
    u16*   s_bf   = (u16*)(gate_q + (long)MQ * RANK);
    u16*   q_bf   = s_bf + (long)MK * DIMD;
    u16*   ctx_bf = q_bf + (long)MQ * DIMD;
    u16*   Btkv   = ctx_bf + (long)MQ * DIMD;   // 1152 rows x 512
    u16*   Btq    = Btkv + 1152L * DIMD;        // 640 rows x 512
    u16*   Bto    = Btq + 640L * DIMD;          // 512 rows x 512
    float* out = (float*)d_out;

    // FiLM conditioning
    film_h_kernel<<<16, 256, 0, stream>>>(ctx0, ctx1, Wc0, bc0, Wc1, bc1, h);
    film_gb_kernel<<<16, 256, 0, stream>>>(h, Wf, bfv, gamma, beta);

    // Normalized bf16 activations
    norm_bf16_kernel<0><<<MK, 256, 0, stream>>>(source, kvn_g, kvn_b, nullptr, nullptr, s_bf);
    norm_bf16_kernel<1><<<MQ, 256, 0, stream>>>(query, qn_g, qn_b, gamma, beta, q_bf);

    // Weight prep: transposed bf16 B matrices + fused gate weights + bias concat
    transpose_bf16_kernel<<<dim3(16, 16), 256, 0, stream>>>(Wk, Btkv, 512, 0);
    transpose_bf16_kernel<<<dim3(16, 16), 256, 0, stream>>>(Wv, Btkv, 512, 512);
    gatefuse_kernel<<<64, 256, 0, stream>>>(Wk, Wgk, Btkv, 1024);
    transpose_bf16_kernel<<<dim3(16, 16), 256, 0, stream>>>(Wq, Btq, 512, 0);
    gatefuse_kernel<<<64, 256, 0, stream>>>(Wq, Wgq, Btq, 512);
    transpose_bf16_kernel<<<dim3(16, 16), 256, 0, stream>>>(Wo, Bto, 512, 0);
    biascat3_kernel<<<5, 256, 0, stream>>>(bk, bv, Wgk, biaskv);
    biascat2_kernel<<<3, 256, 0, stream>>>(bq, Wgq, biasq);

    // Projections via bf16 MFMA
    gemm_mfma_kernel<3><<<dim3(9, MK / 128), 256, 0, stream>>>(
        s_bf, Btkv, biaskv, k_p, v_p, gate_k, 1056);
    gemm_mfma_kernel<2><<<dim3(5, MQ / 128), 256, 0, stream>>>(
        q_bf, Btq, biasq, q_p, nullptr, gate_q, 544);

    // Local attention -> ctx (bf16)
    attn_kernel<<<BATCH * QS, 256, 0, stream>>>(q_p, k_p, v_p, gate_q, gate_k, ctx_bf);

    // Output projection
    gemm_mfma_kernel<1><<<dim3(4, MQ / 128), 256, 0, stream>>>(
        ctx_bf, Bto, bo, out, nullptr, nullptr, 512);
}

// Round 3
// 530.029 us; speedup vs baseline: 1.9878x; 1.1848x over previous
//
#include <hip/hip_runtime.h>
#include <math.h>

// Problem constants
#define DIMD 512
#define QS 64
#define KS 256
#define WIN 4
#define BATCH 8
#define RANK 32
#define NQ 1024             // q tokens per batch
#define NK 4096             // kv tokens per batch
#define MQ (BATCH*NQ)       // 8192 q rows
#define MK (BATCH*NK)       // 32768 kv rows

typedef unsigned short u16;
typedef __attribute__((ext_vector_type(8))) short bf16x8;  // MFMA A/B frag (8 bf16)
typedef __attribute__((ext_vector_type(4))) float f32x4;   // MFMA C/D frag

__device__ inline u16 f2bf(float x) {
    union { float f; unsigned int u; } v; v.f = x;
    unsigned int r = v.u + 0x7FFF + ((v.u >> 16) & 1);
    return (u16)(r >> 16);
}
__device__ inline float bf2f(u16 x) {
    union { unsigned int u; float f; } v; v.u = ((unsigned int)x) << 16;
    return v.f;
}

// ---------------------------------------------------------------------------
// FiLM conditioning: h = silu(ctx0@Wc0 + bc0 + ctx1@Wc1 + bc1)   [8,512]
// 64 blocks: (b, 64-d chunk); 4 threads per output d (i-split), shfl reduce.
// ---------------------------------------------------------------------------
__global__ __launch_bounds__(256) void film_h_kernel(
    const float* __restrict__ ctx0, const float* __restrict__ ctx1,
    const float* __restrict__ Wc0, const float* __restrict__ bc0,
    const float* __restrict__ Wc1, const float* __restrict__ bc1,
    float* __restrict__ h)
{
    int b = blockIdx.x >> 3;
    int d0 = (blockIdx.x & 7) * 64;
    int t = threadIdx.x;
    int dl = t >> 2, p = t & 3;
    int d = d0 + dl;
    const float* c0 = ctx0 + b * DIMD;
    const float* c1 = ctx1 + b * DIMD;
    float acc = 0.f;
    #pragma unroll 4
    for (int ii = 0; ii < 128; ii++) {
        int i = p * 128 + ii;
        acc = fmaf(c0[i], Wc0[i * DIMD + d], acc);
        acc = fmaf(c1[i], Wc1[i * DIMD + d], acc);
    }
    acc += __shfl_xor(acc, 1);
    acc += __shfl_xor(acc, 2);
    if (p == 0) {
        float v = acc + bc0[d] + bc1[d];
        h[b * DIMD + d] = v / (1.f + expf(-v));
    }
}

// gamma,beta = split(h @ Wf + bf)  Wf: [512, 1024]
__global__ __launch_bounds__(256) void film_gb_kernel(
    const float* __restrict__ h, const float* __restrict__ Wf,
    const float* __restrict__ bfv,
    float* __restrict__ gamma, float* __restrict__ beta)
{
    int b = blockIdx.x >> 3;
    int d0 = (blockIdx.x & 7) * 64;
    int t = threadIdx.x;
    int dl = t >> 2, p = t & 3;
    int d = d0 + dl;
    const float* hb = h + b * DIMD;
    float ga = 0.f, be = 0.f;
    #pragma unroll 4
    for (int ii = 0; ii < 128; ii++) {
        int i = p * 128 + ii;
        float hv = hb[i];
        ga = fmaf(hv, Wf[i * 2 * DIMD + d], ga);
        be = fmaf(hv, Wf[i * 2 * DIMD + DIMD + d], be);
    }
    ga += __shfl_xor(ga, 1); ga += __shfl_xor(ga, 2);
    be += __shfl_xor(be, 1); be += __shfl_xor(be, 2);
    if (p == 0) {
        gamma[b * DIMD + d] = ga + bfv[d];
        beta[b * DIMD + d]  = be + bfv[DIMD + d];
    }
}

// ---------------------------------------------------------------------------
// Fused LN (+FiLM) -> bf16. One block per row.
// ---------------------------------------------------------------------------
template<int FILM>
__global__ __launch_bounds__(256) void norm_bf16_kernel(
    const float* __restrict__ X, const float* __restrict__ g, const float* __restrict__ bb,
    const float* __restrict__ gamma, const float* __restrict__ beta,
    u16* __restrict__ out)
{
    int row = blockIdx.x;
    const float* x = X + (long)row * DIMD;
    int t = threadIdx.x;
    float a0 = x[t], a1 = x[t + 256];
    float s = a0 + a1, ss = a0 * a0 + a1 * a1;
    #pragma unroll
    for (int o = 32; o >= 1; o >>= 1) {
        s  += __shfl_down(s, o);
        ss += __shfl_down(ss, o);
    }
    __shared__ float ls[4], lss[4];
    if ((t & 63) == 0) { ls[t >> 6] = s; lss[t >> 6] = ss; }
    __syncthreads();
    float S = ls[0] + ls[1] + ls[2] + ls[3];
    float SS = lss[0] + lss[1] + lss[2] + lss[3];
    float mu = S * (1.f / DIMD);
    float var = SS * (1.f / DIMD) - mu * mu;
    float rs = rsqrtf(var + 1e-5f);
    float v0 = (a0 - mu) * rs * g[t] + bb[t];
    float v1 = (a1 - mu) * rs * g[t + 256] + bb[t + 256];
    if (FILM) {
        int bt = row >> 10;
        v0 = v0 * (1.f + gamma[bt * DIMD + t]) + beta[bt * DIMD + t];
        v1 = v1 * (1.f + gamma[bt * DIMD + t + 256]) + beta[bt * DIMD + t + 256];
    }
    out[(long)row * DIMD + t] = f2bf(v0);
    out[(long)row * DIMD + t + 256] = f2bf(v1);
}

// ---------------------------------------------------------------------------
// Transpose fp32 W[512][ncols] -> bf16 dst rows: dst[dst_row_off + n][k] = W[k][n]
// ---------------------------------------------------------------------------
__global__ __launch_bounds__(256) void transpose_bf16_kernel(
    const float* __restrict__ src, u16* __restrict__ dst, int ncols, int dst_row_off)
{
    __shared__ float tile[32][33];
    int t = threadIdx.x;
    int tx = t & 31, ty = t >> 5;
    int bx = blockIdx.x * 32;
    int by = blockIdx.y * 32;
    #pragma unroll
    for (int i = 0; i < 4; i++)
        tile[ty + i * 8][tx] = src[(long)(by + ty + i * 8) * ncols + bx + tx];
    __syncthreads();
    #pragma unroll
    for (int i = 0; i < 4; i++)
        dst[(long)(dst_row_off + bx + ty + i * 8) * DIMD + by + tx] = f2bf(tile[tx][ty + i * 8]);
}

// ---------------------------------------------------------------------------
// Fused gate weight: dst[dst_row_off + r][k] = sum_j W[k][j] * Wg[j][r]  (r<32)
// ---------------------------------------------------------------------------
__global__ __launch_bounds__(256) void gatefuse_kernel(
    const float* __restrict__ W, const float* __restrict__ Wg,
    u16* __restrict__ dst, int dst_row_off)
{
    int idx = blockIdx.x * 256 + threadIdx.x;
    int r = idx & 31, k = idx >> 5;
    float acc = 0.f;
    #pragma unroll 4
    for (int j = 0; j < DIMD; j++) acc = fmaf(W[k * DIMD + j], Wg[j * RANK + r], acc);
    dst[(long)(dst_row_off + r) * DIMD + k] = f2bf(acc);
}

__global__ __launch_bounds__(256) void biascat3_kernel(
    const float* __restrict__ b0, const float* __restrict__ b1,
    const float* __restrict__ Wg, float* __restrict__ dst)
{
    int t = blockIdx.x * 256 + threadIdx.x;
    if (t < 512) dst[t] = b0[t];
    else if (t < 1024) dst[t] = b1[t - 512];
    else if (t < 1056) {
        int r = t - 1024;
        float a = 0.f;
        for (int j = 0; j < DIMD; j++) a = fmaf(b0[j], Wg[j * RANK + r], a);
        dst[t] = a;
    }
}

__global__ __launch_bounds__(256) void biascat2_kernel(
    const float* __restrict__ b0, const float* __restrict__ Wg, float* __restrict__ dst)
{
    int t = blockIdx.x * 256 + threadIdx.x;
    if (t < 512) dst[t] = b0[t];
    else if (t < 544) {
        int r = t - 512;
        float a = 0.f;
        for (int j = 0; j < DIMD; j++) a = fmaf(b0[j], Wg[j * RANK + r], a);
        dst[t] = a;
    }
}

// ---------------------------------------------------------------------------
// bf16 MFMA GEMM:  C = A[M][512]bf16 @ Bt[N][512]bf16^T + biascat
// 128x128 tile, BK=32. LDS stride padded to 40 bf16 (80 B): (5*row + quad) % 8
// spreads frag reads evenly over bank groups (was 8-way at stride 32).
// BF=true: all output sections stored bf16(u16); BF=false: fp32.
// ---------------------------------------------------------------------------
template<int NSEC, bool BF>
__global__ __launch_bounds__(256) void gemm_mfma_kernel(
    const u16* __restrict__ A, const u16* __restrict__ Bt,
    const float* __restrict__ biascat,
    void* __restrict__ C0v, void* __restrict__ C1v, void* __restrict__ Cgv,
    int Nvalid)
{
    __shared__ u16 As[128 * 40];
    __shared__ u16 Bs[128 * 40];
    int t = threadIdx.x;
    int wave = t >> 6, lane = t & 63;
    int m0 = blockIdx.y * 128;
    int n0 = blockIdx.x * 128;
    int mhalf = (wave >> 1) * 64, nhalf = (wave & 1) * 64;
    int lm = lane & 15, quad = lane >> 4;

    f32x4 acc[4][4];
    #pragma unroll
    for (int i = 0; i < 4; i++)
        #pragma unroll
        for (int j = 0; j < 4; j++)
            acc[i][j] = (f32x4){0.f, 0.f, 0.f, 0.f};

    for (int k0 = 0; k0 < DIMD; k0 += 32) {
        __syncthreads();
        #pragma unroll
        for (int u = 0; u < 2; u++) {
            int L = t + u * 256;              // 0..511
            int r = L >> 2;                   // row 0..127
            int c = L & 3;                    // int4 index (8 bf16)
            *(int4*)&As[r * 40 + c * 8] = *(const int4*)&A[(long)(m0 + r) * DIMD + k0 + c * 8];
            *(int4*)&Bs[r * 40 + c * 8] = *(const int4*)&Bt[(long)(n0 + r) * DIMD + k0 + c * 8];
        }
        __syncthreads();
        bf16x8 af[4], bfr[4];
        #pragma unroll
        for (int i = 0; i < 4; i++) {
            af[i]  = *(const bf16x8*)&As[(mhalf + i * 16 + lm) * 40 + quad * 8];
            bfr[i] = *(const bf16x8*)&Bs[(nhalf + i * 16 + lm) * 40 + quad * 8];
        }
        #pragma unroll
        for (int i = 0; i < 4; i++)
            #pragma unroll
            for (int j = 0; j < 4; j++)
                acc[i][j] = __builtin_amdgcn_mfma_f32_16x16x32_bf16(af[i], bfr[j], acc[i][j], 0, 0, 0);
    }

    #pragma unroll
    for (int j = 0; j < 4; j++) {
        int col = n0 + nhalf + j * 16 + lm;
        if (col >= Nvalid) continue;
        float bias = biascat[col];
        void* dst; int cw, ccol;
        if (NSEC == 1) { dst = C0v; cw = 512; ccol = col; }
        else if (NSEC == 2) {
            if (col < 512) { dst = C0v; cw = 512; ccol = col; }
            else           { dst = Cgv; cw = 32;  ccol = col - 512; }
        } else {
            if (col < 512)       { dst = C0v; cw = 512; ccol = col; }
            else if (col < 1024) { dst = C1v; cw = 512; ccol = col - 512; }
            else                 { dst = Cgv; cw = 32;  ccol = col - 1024; }
        }
        #pragma unroll
        for (int i = 0; i < 4; i++) {
            int row0 = m0 + mhalf + i * 16 + quad * 4;
            #pragma unroll
            for (int r = 0; r < 4; r++) {
                float v = acc[i][j][r] + bias;
                if (BF) ((u16*)dst)[(long)(row0 + r) * cw + ccol] = f2bf(v);
                else    ((float*)dst)[(long)(row0 + r) * cw + ccol] = v;
            }
        }
    }
}

// ---------------------------------------------------------------------------
// Flash-style local attention, MFMA, bf16 in/out, fp32 online softmax.
// One block per (b, q-step): 16 q rows x nst*16 kv rows (nst in 5..9).
// Per step s (16 kv rows): stage K (swizzled) + V (transposed+swizzled) from
// prefetch regs; S = Q@K^T via 4-way K-split MFMA (+gate MFMA on wave 3);
// online softmax (m,l in regs); PV over step PAIRS with K=32 MFMA; P bf16 in
// LDS with mid-pair alpha rescale. Only the verified 16x16x32_bf16 intrinsic.
// ---------------------------------------------------------------------------
__global__ __launch_bounds__(256, 2) void attn_kernel(
    const u16* __restrict__ q_bf, const u16* __restrict__ k_bf,
    const u16* __restrict__ v_bf, const u16* __restrict__ gq_bf,
    const u16* __restrict__ gk_bf, u16* __restrict__ ctx)
{
    __shared__ u16 Ks[16 * 512];        // [kv row][k], 16B units XOR-swizzled by row&7
    __shared__ u16 Vt[512 * 32];        // [d][kv-pair], 16B units XOR-swizzled by d&3
    __shared__ u16 Pb[16 * 40];         // P bf16, [q][pair kv], stride 40
    __shared__ float part[4][16][16];   // S partials per wave [q][kv]
    __shared__ float Gb[16][16];        // gate logits
    __shared__ float alphap[16];        // pair-product alpha per q row
    __shared__ float linv[16];

    int blk = blockIdx.x;
    int b = blk >> 6, qs = blk & 63;
    int center = (int)(qs * (255.0f / 63.0f) + 0.5f);
    int lo = center - WIN; if (lo < 0) lo = 0;
    int hi = center + WIN; if (hi > KS - 1) hi = KS - 1;
    int nst = hi - lo + 1;
    long rowq0 = (long)b * NQ + qs * 16;
    long rowk0 = (long)b * NK + lo * 16;

    int t = threadIdx.x;
    int wave = t >> 6, lane = t & 63;
    int lm = lane & 15, quad = lane >> 4;
    int qi = t >> 4, ki = t & 15;

    // Q fragments: wave w covers k in [w*128, w*128+128): 4 frags
    bf16x8 qf[4];
    #pragma unroll
    for (int f = 0; f < 4; f++)
        qf[f] = *(const bf16x8*)&q_bf[(rowq0 + lm) * DIMD + wave * 128 + f * 32 + quad * 8];
    bf16x8 gqf;
    if (wave == 3) gqf = *(const bf16x8*)&gq_bf[(rowq0 + lm) * RANK + quad * 8];

    // prefetch step 0 (K: 4 int4/thread, V: 4 int4/thread)
    int4 kpre[4], vpre[4];
    #pragma unroll
    for (int u = 0; u < 4; u++) {
        int idx = u * 256 + t;
        kpre[u] = *(const int4*)&k_bf[(rowk0 + (idx >> 6)) * DIMD + (idx & 63) * 8];
        int vkv = (idx >> 2) & 15, vdc = (idx & 3) | ((idx >> 6) << 2);
        vpre[u] = *(const int4*)&v_bf[(rowk0 + vkv) * DIMD + vdc * 8];
    }

    float m_run = -1e30f, l_run = 0.f;
    f32x4 acc[8];
    #pragma unroll
    for (int j = 0; j < 8; j++) acc[j] = (f32x4){0.f, 0.f, 0.f, 0.f};

    const float scale = 0.044194173824159216f;   // 512^-0.5
    const float grs = 0.17677669529663687f;      // 32^-0.5

    for (int s = 0; s < nst; s++) {
        int half = s & 1;
        // ---- s0: write prefetched regs into LDS ----
        #pragma unroll
        for (int u = 0; u < 4; u++) {
            int idx = u * 256 + t;
            int row = idx >> 6, c = idx & 63;
            *(int4*)&Ks[row * 512 + (c ^ (row & 7)) * 8] = kpre[u];
            int vkv = (idx >> 2) & 15, vdc = (idx & 3) | ((idx >> 6) << 2);
            int kvp = half * 16 + vkv;
            u16 vv[8];
            *(int4*)vv = vpre[u];
            #pragma unroll
            for (int i = 0; i < 8; i++) {
                int d = vdc * 8 + i;
                Vt[d * 32 + (((kvp >> 3) ^ (d & 3)) << 3) + (kvp & 7)] = vv[i];
            }
        }
        __syncthreads();
        // ---- s1: prefetch next step; S MFMAs (K-split) + gate MFMA ----
        if (s + 1 < nst) {
            long rk = rowk0 + (long)(s + 1) * 16;
            #pragma unroll
            for (int u = 0; u < 4; u++) {
                int idx = u * 256 + t;
                kpre[u] = *(const int4*)&k_bf[(rk + (idx >> 6)) * DIMD + (idx & 63) * 8];
                int vkv = (idx >> 2) & 15, vdc = (idx & 3) | ((idx >> 6) << 2);
                vpre[u] = *(const int4*)&v_bf[(rk + vkv) * DIMD + vdc * 8];
            }
        }
        f32x4 sacc = (f32x4){0.f, 0.f, 0.f, 0.f};
        #pragma unroll
        for (int f = 0; f < 4; f++) {
            int cidx = wave * 16 + f * 4 + quad;          // 16B-unit index along k
            bf16x8 kf = *(const bf16x8*)&Ks[lm * 512 + (cidx ^ (lm & 7)) * 8];
            sacc = __builtin_amdgcn_mfma_f32_16x16x32_bf16(qf[f], kf, sacc, 0, 0, 0);
        }
        #pragma unroll
        for (int r = 0; r < 4; r++) part[wave][quad * 4 + r][lm] = sacc[r];
        if (wave == 3) {
            bf16x8 gkf = *(const bf16x8*)&gk_bf[(rowk0 + (long)s * 16 + lm) * RANK + quad * 8];
            f32x4 gacc = (f32x4){0.f, 0.f, 0.f, 0.f};
            gacc = __builtin_amdgcn_mfma_f32_16x16x32_bf16(gqf, gkf, gacc, 0, 0, 0);
            #pragma unroll
            for (int r = 0; r < 4; r++) Gb[quad * 4 + r][lm] = gacc[r];
        }
        __syncthreads();
        // ---- s2: online softmax; thread (qi,ki) owns one score ----
        float sv = (part[0][qi][ki] + part[1][qi][ki] + part[2][qi][ki] + part[3][qi][ki]) * scale;
        float gl = Gb[qi][ki] * grs;
        float sig = 1.f / (1.f + expf(-gl));
        sv += logf(sig + 1e-6f);
        float mx = sv;
        mx = fmaxf(mx, __shfl_xor(mx, 1));
        mx = fmaxf(mx, __shfl_xor(mx, 2));
        mx = fmaxf(mx, __shfl_xor(mx, 4));
        mx = fmaxf(mx, __shfl_xor(mx, 8));
        float m_new = fmaxf(m_run, mx);
        float p = expf(sv - m_new);
        float ps = p;
        ps += __shfl_xor(ps, 1);
        ps += __shfl_xor(ps, 2);
        ps += __shfl_xor(ps, 4);
        ps += __shfl_xor(ps, 8);
        float alpha = expf(m_run - m_new);
        l_run = l_run * alpha + ps;
        m_run = m_new;
        Pb[qi * 40 + half * 16 + ki] = f2bf(p);
        if (half == 1) {
            // rescale first half of the pair by this step's alpha
            Pb[qi * 40 + ki] = f2bf(bf2f(Pb[qi * 40 + ki]) * alpha);
        }
        bool dopv = (half == 1) || (s == nst - 1);
        if (dopv && half == 0) Pb[qi * 40 + 16 + ki] = 0;   // zero unused half
        if (ki == 0) {
            if (half == 0) alphap[qi] = alpha;
            else           alphap[qi] *= alpha;
            if (s == nst - 1) linv[qi] = 1.f / l_run;
        }
        __syncthreads();
        // ---- s3: PV round over the pair (K=32) ----
        if (dopv) {
            float ar[4];
            #pragma unroll
            for (int r = 0; r < 4; r++) ar[r] = alphap[quad * 4 + r];
            #pragma unroll
            for (int j = 0; j < 8; j++)
                #pragma unroll
                for (int r = 0; r < 4; r++) acc[j][r] *= ar[r];
            bf16x8 pf = *(const bf16x8*)&Pb[lm * 40 + quad * 8];
            #pragma unroll
            for (int j = 0; j < 8; j++) {
                int d = wave * 128 + j * 16 + lm;
                bf16x8 vf = *(const bf16x8*)&Vt[d * 32 + ((quad ^ (d & 3)) << 3)];
                acc[j] = __builtin_amdgcn_mfma_f32_16x16x32_bf16(pf, vf, acc[j], 0, 0, 0);
            }
            __syncthreads();
        }
    }
    // ---- epilogue: O * (1/l) -> bf16 ctx ----
    float li[4];
    #pragma unroll
    for (int r = 0; r < 4; r++) li[r] = linv[quad * 4 + r];
    #pragma unroll
    for (int j = 0; j < 8; j++) {
        int d = wave * 128 + j * 16 + lm;
        #pragma unroll
        for (int r = 0; r < 4; r++)
            ctx[(rowq0 + quad * 4 + r) * DIMD + d] = f2bf(acc[j][r] * li[r]);
    }
}

// ---------------------------------------------------------------------------
extern "C" void kernel_launch(void* const* d_in, const int* in_sizes, int n_in,
                              void* d_out, int out_size, void* d_ws, size_t ws_size,
                              hipStream_t stream) {
    const float* query  = (const float*)d_in[0];
    const float* source = (const float*)d_in[1];
    const float* ctx0   = (const float*)d_in[2];
    const float* ctx1   = (const float*)d_in[3];
    // d_in[4] = mask: structurally known local window, unused
    const float* qn_g  = (const float*)d_in[5];
    const float* qn_b  = (const float*)d_in[6];
    const float* kvn_g = (const float*)d_in[7];
    const float* kvn_b = (const float*)d_in[8];
    const float* Wq = (const float*)d_in[9];   const float* bq = (const float*)d_in[10];
    const float* Wk = (const float*)d_in[11];  const float* bk = (const float*)d_in[12];
    const float* Wv = (const float*)d_in[13];  const float* bv = (const float*)d_in[14];
    const float* Wo = (const float*)d_in[15];  const float* bo = (const float*)d_in[16];
    const float* Wgq = (const float*)d_in[17];
    const float* Wgk = (const float*)d_in[18];
    const float* Wc0 = (const float*)d_in[19]; const float* bc0 = (const float*)d_in[20];
    const float* Wc1 = (const float*)d_in[21]; const float* bc1 = (const float*)d_in[22];
    const float* Wf  = (const float*)d_in[23]; const float* bfv = (const float*)d_in[24];

    // ---- workspace layout ----
    float* ws = (float*)d_ws;
    float* h      = ws;                         // 4096
    float* gamma  = h + 4096;                   // 4096
    float* beta   = gamma + 4096;               // 4096
    float* biaskv = beta + 4096;                // 1088
    float* biasq  = biaskv + 1088;              // 576
    u16* u = (u16*)(biasq + 576);
    u16* sln  = u;                 u += (long)MK * DIMD;   // LN(source) bf16
    u16* qln  = u;                 u += (long)MQ * DIMD;   // LN+FiLM(query) bf16
    u16* kp   = u;                 u += (long)MK * DIMD;   // k proj bf16
    u16* vp   = u;                 u += (long)MK * DIMD;   // v proj bf16
    u16* gk   = u;                 u += (long)MK * RANK;   // gate_k bf16
    u16* gq   = u;                 u += (long)MQ * RANK;   // gate_q bf16
    u16* qp   = u;                 u += (long)MQ * DIMD;   // q proj bf16
    u16* ctxb = u;                 u += (long)MQ * DIMD;   // attention output bf16
    u16* Btkv = u;                 u += 1152L * DIMD;      // [Wk^T | Wv^T | (Wk·Wgk)^T]
    u16* Btq  = u;                 u += 640L * DIMD;       // [Wq^T | (Wq·Wgq)^T]
    u16* Bto  = u;                 u += 512L * DIMD;       // Wo^T
    float* out = (float*)d_out;

    // FiLM conditioning
    film_h_kernel<<<64, 256, 0, stream>>>(ctx0, ctx1, Wc0, bc0, Wc1, bc1, h);
    film_gb_kernel<<<64, 256, 0, stream>>>(h, Wf, bfv, gamma, beta);

    // Normalized bf16 activations
    norm_bf16_kernel<0><<<MK, 256, 0, stream>>>(source, kvn_g, kvn_b, nullptr, nullptr, sln);
    norm_bf16_kernel<1><<<MQ, 256, 0, stream>>>(query, qn_g, qn_b, gamma, beta, qln);

    // Weight prep
    transpose_bf16_kernel<<<dim3(16, 16), 256, 0, stream>>>(Wk, Btkv, 512, 0);
    transpose_bf16_kernel<<<dim3(16, 16), 256, 0, stream>>>(Wv, Btkv, 512, 512);
    gatefuse_kernel<<<64, 256, 0, stream>>>(Wk, Wgk, Btkv, 1024);
    transpose_bf16_kernel<<<dim3(16, 16), 256, 0, stream>>>(Wq, Btq, 512, 0);
    gatefuse_kernel<<<64, 256, 0, stream>>>(Wq, Wgq, Btq, 512);
    transpose_bf16_kernel<<<dim3(16, 16), 256, 0, stream>>>(Wo, Bto, 512, 0);
    biascat3_kernel<<<5, 256, 0, stream>>>(bk, bv, Wgk, biaskv);
    biascat2_kernel<<<3, 256, 0, stream>>>(bq, Wgq, biasq);

    // Projections (bf16 outputs)
    gemm_mfma_kernel<3, true><<<dim3(9, MK / 128), 256, 0, stream>>>(
        sln, Btkv, biaskv, kp, vp, gk, 1056);
    gemm_mfma_kernel<2, true><<<dim3(5, MQ / 128), 256, 0, stream>>>(
        qln, Btq, biasq, qp, nullptr, gq, 544);

    // Flash local attention
    attn_kernel<<<BATCH * QS, 256, 0, stream>>>(qp, kp, vp, gq, gk, ctxb);

    // Output projection (fp32 out)
    gemm_mfma_kernel<1, false><<<dim3(4, MQ / 128), 256, 0, stream>>>(
        ctxb, Bto, bo, out, nullptr, nullptr, 512);
}

// Round 4
// 478.710 us; speedup vs baseline: 2.2009x; 1.1072x over previous
//
#include <hip/hip_runtime.h>
#include <math.h>

// Problem constants
#define DIMD 512
#define QS 64
#define KS 256
#define WIN 4
#define BATCH 8
#define RANK 32
#define NQ 1024             // q tokens per batch
#define NK 4096             // kv tokens per batch
#define MQ (BATCH*NQ)       // 8192 q rows
#define MK (BATCH*NK)       // 32768 kv rows

typedef unsigned short u16;
typedef __attribute__((ext_vector_type(8))) short bf16x8;  // MFMA A/B frag (8 bf16)
typedef __attribute__((ext_vector_type(4))) float f32x4;   // MFMA C/D frag

__device__ inline u16 f2bf(float x) {
    union { float f; unsigned int u; } v; v.f = x;
    unsigned int r = v.u + 0x7FFF + ((v.u >> 16) & 1);
    return (u16)(r >> 16);
}
__device__ inline float bf2f(u16 x) {
    union { unsigned int u; float f; } v; v.u = ((unsigned int)x) << 16;
    return v.f;
}

// async global->LDS, 16 B per lane. HW: LDS dest = wave-uniform base + lane*16.
// Caller arranges lane i's lds ptr == base + i*16 so the contract matches.
__device__ __forceinline__ void gload16(const u16* g, u16* l) {
    __builtin_amdgcn_global_load_lds(
        (const __attribute__((address_space(1))) void*)g,
        (__attribute__((address_space(3))) void*)l, 16, 0, 0);
}

// ---------------------------------------------------------------------------
// FiLM conditioning: h = silu(ctx0@Wc0 + bc0 + ctx1@Wc1 + bc1)   [8,512]
// ---------------------------------------------------------------------------
__global__ __launch_bounds__(256) void film_h_kernel(
    const float* __restrict__ ctx0, const float* __restrict__ ctx1,
    const float* __restrict__ Wc0, const float* __restrict__ bc0,
    const float* __restrict__ Wc1, const float* __restrict__ bc1,
    float* __restrict__ h)
{
    int b = blockIdx.x >> 3;
    int d0 = (blockIdx.x & 7) * 64;
    int t = threadIdx.x;
    int dl = t >> 2, p = t & 3;
    int d = d0 + dl;
    const float* c0 = ctx0 + b * DIMD;
    const float* c1 = ctx1 + b * DIMD;
    float acc = 0.f;
    #pragma unroll 4
    for (int ii = 0; ii < 128; ii++) {
        int i = p * 128 + ii;
        acc = fmaf(c0[i], Wc0[i * DIMD + d], acc);
        acc = fmaf(c1[i], Wc1[i * DIMD + d], acc);
    }
    acc += __shfl_xor(acc, 1);
    acc += __shfl_xor(acc, 2);
    if (p == 0) {
        float v = acc + bc0[d] + bc1[d];
        h[b * DIMD + d] = v / (1.f + expf(-v));
    }
}

// gamma,beta = split(h @ Wf + bf)  Wf: [512, 1024]
__global__ __launch_bounds__(256) void film_gb_kernel(
    const float* __restrict__ h, const float* __restrict__ Wf,
    const float* __restrict__ bfv,
    float* __restrict__ gamma, float* __restrict__ beta)
{
    int b = blockIdx.x >> 3;
    int d0 = (blockIdx.x & 7) * 64;
    int t = threadIdx.x;
    int dl = t >> 2, p = t & 3;
    int d = d0 + dl;
    const float* hb = h + b * DIMD;
    float ga = 0.f, be = 0.f;
    #pragma unroll 4
    for (int ii = 0; ii < 128; ii++) {
        int i = p * 128 + ii;
        float hv = hb[i];
        ga = fmaf(hv, Wf[i * 2 * DIMD + d], ga);
        be = fmaf(hv, Wf[i * 2 * DIMD + DIMD + d], be);
    }
    ga += __shfl_xor(ga, 1); ga += __shfl_xor(ga, 2);
    be += __shfl_xor(be, 1); be += __shfl_xor(be, 2);
    if (p == 0) {
        gamma[b * DIMD + d] = ga + bfv[d];
        beta[b * DIMD + d]  = be + bfv[DIMD + d];
    }
}

// ---------------------------------------------------------------------------
// Fused LN (+FiLM) -> bf16. One WAVE per row, 4 rows/block, float4 loads,
// 16B stores. No block barrier.
// ---------------------------------------------------------------------------
template<int FILM>
__global__ __launch_bounds__(256) void norm_bf16_kernel(
    const float* __restrict__ X, const float* __restrict__ g, const float* __restrict__ bb,
    const float* __restrict__ gamma, const float* __restrict__ beta,
    u16* __restrict__ out)
{
    int wave = threadIdx.x >> 6, lane = threadIdx.x & 63;
    long row = (long)blockIdx.x * 4 + wave;
    const float* x = X + row * DIMD;
    int c = lane * 8;
    float4 a = *(const float4*)&x[c];
    float4 b = *(const float4*)&x[c + 4];
    float s  = a.x + a.y + a.z + a.w + b.x + b.y + b.z + b.w;
    float ss = a.x*a.x + a.y*a.y + a.z*a.z + a.w*a.w
             + b.x*b.x + b.y*b.y + b.z*b.z + b.w*b.w;
    #pragma unroll
    for (int o = 1; o < 64; o <<= 1) { s += __shfl_xor(s, o); ss += __shfl_xor(ss, o); }
    float mu = s * (1.f / DIMD);
    float var = ss * (1.f / DIMD) - mu * mu;
    float rs = rsqrtf(var + 1e-5f);
    float4 g0 = *(const float4*)&g[c],  g1 = *(const float4*)&g[c + 4];
    float4 b0 = *(const float4*)&bb[c], b1 = *(const float4*)&bb[c + 4];
    float v[8];
    v[0] = (a.x - mu) * rs * g0.x + b0.x;
    v[1] = (a.y - mu) * rs * g0.y + b0.y;
    v[2] = (a.z - mu) * rs * g0.z + b0.z;
    v[3] = (a.w - mu) * rs * g0.w + b0.w;
    v[4] = (b.x - mu) * rs * g1.x + b1.x;
    v[5] = (b.y - mu) * rs * g1.y + b1.y;
    v[6] = (b.z - mu) * rs * g1.z + b1.z;
    v[7] = (b.w - mu) * rs * g1.w + b1.w;
    if (FILM) {
        int bt = (int)(row >> 10);
        const float* gp = gamma + bt * DIMD + c;
        const float* bp = beta + bt * DIMD + c;
        float4 gm0 = *(const float4*)gp, gm1 = *(const float4*)(gp + 4);
        float4 be0 = *(const float4*)bp, be1 = *(const float4*)(bp + 4);
        v[0] = v[0] * (1.f + gm0.x) + be0.x;
        v[1] = v[1] * (1.f + gm0.y) + be0.y;
        v[2] = v[2] * (1.f + gm0.z) + be0.z;
        v[3] = v[3] * (1.f + gm0.w) + be0.w;
        v[4] = v[4] * (1.f + gm1.x) + be1.x;
        v[5] = v[5] * (1.f + gm1.y) + be1.y;
        v[6] = v[6] * (1.f + gm1.z) + be1.z;
        v[7] = v[7] * (1.f + gm1.w) + be1.w;
    }
    u16 o8[8];
    #pragma unroll
    for (int e = 0; e < 8; e++) o8[e] = f2bf(v[e]);
    *(int4*)&out[row * DIMD + c] = *(const int4*)o8;
}

// ---------------------------------------------------------------------------
// Transpose fp32 W[512][ncols] -> bf16 dst rows: dst[dst_row_off + n][k] = W[k][n]
// ---------------------------------------------------------------------------
__global__ __launch_bounds__(256) void transpose_bf16_kernel(
    const float* __restrict__ src, u16* __restrict__ dst, int ncols, int dst_row_off)
{
    __shared__ float tile[32][33];
    int t = threadIdx.x;
    int tx = t & 31, ty = t >> 5;
    int bx = blockIdx.x * 32;
    int by = blockIdx.y * 32;
    #pragma unroll
    for (int i = 0; i < 4; i++)
        tile[ty + i * 8][tx] = src[(long)(by + ty + i * 8) * ncols + bx + tx];
    __syncthreads();
    #pragma unroll
    for (int i = 0; i < 4; i++)
        dst[(long)(dst_row_off + bx + ty + i * 8) * DIMD + by + tx] = f2bf(tile[tx][ty + i * 8]);
}

// ---------------------------------------------------------------------------
// Fused gate weight: dst[dst_row_off + r][k] = sum_j W[k][j] * Wg[j][r]  (r<32)
// ---------------------------------------------------------------------------
__global__ __launch_bounds__(256) void gatefuse_kernel(
    const float* __restrict__ W, const float* __restrict__ Wg,
    u16* __restrict__ dst, int dst_row_off)
{
    int idx = blockIdx.x * 256 + threadIdx.x;
    int r = idx & 31, k = idx >> 5;
    float acc = 0.f;
    #pragma unroll 4
    for (int j = 0; j < DIMD; j++) acc = fmaf(W[k * DIMD + j], Wg[j * RANK + r], acc);
    dst[(long)(dst_row_off + r) * DIMD + k] = f2bf(acc);
}

__global__ __launch_bounds__(256) void biascat3_kernel(
    const float* __restrict__ b0, const float* __restrict__ b1,
    const float* __restrict__ Wg, float* __restrict__ dst)
{
    int t = blockIdx.x * 256 + threadIdx.x;
    if (t < 512) dst[t] = b0[t];
    else if (t < 1024) dst[t] = b1[t - 512];
    else if (t < 1056) {
        int r = t - 1024;
        float a = 0.f;
        for (int j = 0; j < DIMD; j++) a = fmaf(b0[j], Wg[j * RANK + r], a);
        dst[t] = a;
    }
}

__global__ __launch_bounds__(256) void biascat2_kernel(
    const float* __restrict__ b0, const float* __restrict__ Wg, float* __restrict__ dst)
{
    int t = blockIdx.x * 256 + threadIdx.x;
    if (t < 512) dst[t] = b0[t];
    else if (t < 544) {
        int r = t - 512;
        float a = 0.f;
        for (int j = 0; j < DIMD; j++) a = fmaf(b0[j], Wg[j * RANK + r], a);
        dst[t] = a;
    }
}

// ---------------------------------------------------------------------------
// bf16 MFMA GEMM (m97 structure): C = A[M][512]bf16 @ Bt[N][512]bf16^T + bias
// 128x128 tile, BK=32, global_load_lds width-16 staging into unpadded
// [row][32] LDS tiles, 2-barrier K-loop, LDS-transposed coalesced epilogue.
// 1-D grid with XCD swizzle: xcd = id&7 gets ypg consecutive m-tiles, the nx
// n-blocks of each m-tile consecutive on that XCD (A tile stays L2-resident).
// ---------------------------------------------------------------------------
template<int NSEC, bool BF>
__global__ __launch_bounds__(256) void gemm_mfma_kernel(
    const u16* __restrict__ A, const u16* __restrict__ Bt,
    const float* __restrict__ biascat,
    void* __restrict__ C0v, void* __restrict__ C1v, void* __restrict__ Cgv,
    int Nvalid, int nx, int ypg)
{
    __shared__ u16 smem[8192];          // As[4096] | Bs[4096]  (16 KB)
    u16* As = smem;
    u16* Bs = smem + 4096;

    int t = threadIdx.x;
    int wave = t >> 6, lane = t & 63;
    int id = blockIdx.x;
    int xcd = id & 7, li = id >> 3;
    int by = xcd * ypg + li / nx;
    int bx = li % nx;
    int m0 = by * 128, n0 = bx * 128;
    int mhalf = (wave >> 1) * 64, nhalf = (wave & 1) * 64;
    int lm = lane & 15, quad = lane >> 4;

    // staging addresses: wave w stages rows [w*32, w*32+32) in 2 issues of 16 rows
    int srow = wave * 32 + (lane >> 2);
    int scol = (lane & 3) * 8;
    const u16* Ag = A + (long)(m0 + srow) * DIMD + scol;
    const u16* Bg = Bt + (long)(n0 + srow) * DIMD + scol;
    u16* Asl = As + wave * 1024 + lane * 8;   // lane i at wave base + i*16 B
    u16* Bsl = Bs + wave * 1024 + lane * 8;

    f32x4 acc[4][4];
    #pragma unroll
    for (int i = 0; i < 4; i++)
        #pragma unroll
        for (int j = 0; j < 4; j++)
            acc[i][j] = (f32x4){0.f, 0.f, 0.f, 0.f};

    for (int k0 = 0; k0 < DIMD; k0 += 32) {
        __syncthreads();
        gload16(Ag + k0, Asl);
        gload16(Ag + 16 * DIMD + k0, Asl + 512);
        gload16(Bg + k0, Bsl);
        gload16(Bg + 16 * DIMD + k0, Bsl + 512);
        __syncthreads();
        bf16x8 af[4], bfr[4];
        #pragma unroll
        for (int i = 0; i < 4; i++) {
            af[i]  = *(const bf16x8*)&As[(mhalf + i * 16 + lm) * 32 + quad * 8];
            bfr[i] = *(const bf16x8*)&Bs[(nhalf + i * 16 + lm) * 32 + quad * 8];
        }
        #pragma unroll
        for (int i = 0; i < 4; i++)
            #pragma unroll
            for (int j = 0; j < 4; j++)
                acc[i][j] = __builtin_amdgcn_mfma_f32_16x16x32_bf16(af[i], bfr[j], acc[i][j], 0, 0, 0);
    }

    // biases per j-column (acc col = nhalf + j*16 + lm)
    float biasj[4];
    #pragma unroll
    for (int j = 0; j < 4; j++) biasj[j] = biascat[n0 + nhalf + j * 16 + lm];

    if (BF) {
        // bf16 epilogue: stage 32x128 u16 slice in LDS, store 16B chunks
        for (int i = 0; i < 4; i++) {
            __syncthreads();
            #pragma unroll
            for (int j = 0; j < 4; j++)
                #pragma unroll
                for (int r = 0; r < 4; r++)
                    smem[((wave >> 1) * 16 + quad * 4 + r) * 128 + nhalf + j * 16 + lm] =
                        f2bf(acc[i][j][r] + biasj[j]);
            __syncthreads();
            #pragma unroll
            for (int u = 0; u < 2; u++) {
                int cch = t + u * 256;            // 0..511
                int R = cch >> 4, ci = cch & 15;
                long grow = m0 + (R >> 4) * 64 + i * 16 + (R & 15);
                int gcol = n0 + ci * 8;
                int4 val = *(const int4*)&smem[R * 128 + ci * 8];
                if (NSEC == 1) {
                    *(int4*)((u16*)C0v + grow * 512 + gcol) = val;
                } else if (NSEC == 2) {
                    if (gcol < 512)          *(int4*)((u16*)C0v + grow * 512 + gcol) = val;
                    else if (gcol < Nvalid)  *(int4*)((u16*)Cgv + grow * 32 + (gcol - 512)) = val;
                } else {
                    if (gcol < 512)          *(int4*)((u16*)C0v + grow * 512 + gcol) = val;
                    else if (gcol < 1024)    *(int4*)((u16*)C1v + grow * 512 + (gcol - 512)) = val;
                    else if (gcol < Nvalid)  *(int4*)((u16*)Cgv + grow * 32 + (gcol - 1024)) = val;
                }
            }
        }
    } else {
        // fp32 epilogue: stage 32x128 f32 slice (16 KB = whole smem)
        float* Stg = (float*)smem;
        for (int i = 0; i < 4; i++) {
            __syncthreads();
            #pragma unroll
            for (int j = 0; j < 4; j++)
                #pragma unroll
                for (int r = 0; r < 4; r++)
                    Stg[((wave >> 1) * 16 + quad * 4 + r) * 128 + nhalf + j * 16 + lm] =
                        acc[i][j][r] + biasj[j];
            __syncthreads();
            #pragma unroll
            for (int u = 0; u < 4; u++) {
                int cch = t + u * 256;            // 0..1023
                int R = cch >> 5, ci = cch & 31;
                long grow = m0 + (R >> 4) * 64 + i * 16 + (R & 15);
                int gcol = n0 + ci * 4;
                *(float4*)((float*)C0v + grow * 512 + gcol) = *(const float4*)&Stg[R * 128 + ci * 4];
            }
        }
    }
}

// ---------------------------------------------------------------------------
// Flash-style local attention, MFMA, bf16 in/out, fp32 online softmax.
// (unchanged from round 3)
// ---------------------------------------------------------------------------
__global__ __launch_bounds__(256, 2) void attn_kernel(
    const u16* __restrict__ q_bf, const u16* __restrict__ k_bf,
    const u16* __restrict__ v_bf, const u16* __restrict__ gq_bf,
    const u16* __restrict__ gk_bf, u16* __restrict__ ctx)
{
    __shared__ u16 Ks[16 * 512];        // [kv row][k], 16B units XOR-swizzled by row&7
    __shared__ u16 Vt[512 * 32];        // [d][kv-pair], 16B units XOR-swizzled by d&3
    __shared__ u16 Pb[16 * 40];         // P bf16, [q][pair kv], stride 40
    __shared__ float part[4][16][16];   // S partials per wave [q][kv]
    __shared__ float Gb[16][16];        // gate logits
    __shared__ float alphap[16];        // pair-product alpha per q row
    __shared__ float linv[16];

    int blk = blockIdx.x;
    int b = blk >> 6, qs = blk & 63;
    int center = (int)(qs * (255.0f / 63.0f) + 0.5f);
    int lo = center - WIN; if (lo < 0) lo = 0;
    int hi = center + WIN; if (hi > KS - 1) hi = KS - 1;
    int nst = hi - lo + 1;
    long rowq0 = (long)b * NQ + qs * 16;
    long rowk0 = (long)b * NK + lo * 16;

    int t = threadIdx.x;
    int wave = t >> 6, lane = t & 63;
    int lm = lane & 15, quad = lane >> 4;
    int qi = t >> 4, ki = t & 15;

    bf16x8 qf[4];
    #pragma unroll
    for (int f = 0; f < 4; f++)
        qf[f] = *(const bf16x8*)&q_bf[(rowq0 + lm) * DIMD + wave * 128 + f * 32 + quad * 8];
    bf16x8 gqf;
    if (wave == 3) gqf = *(const bf16x8*)&gq_bf[(rowq0 + lm) * RANK + quad * 8];

    int4 kpre[4], vpre[4];
    #pragma unroll
    for (int u = 0; u < 4; u++) {
        int idx = u * 256 + t;
        kpre[u] = *(const int4*)&k_bf[(rowk0 + (idx >> 6)) * DIMD + (idx & 63) * 8];
        int vkv = (idx >> 2) & 15, vdc = (idx & 3) | ((idx >> 6) << 2);
        vpre[u] = *(const int4*)&v_bf[(rowk0 + vkv) * DIMD + vdc * 8];
    }

    float m_run = -1e30f, l_run = 0.f;
    f32x4 acc[8];
    #pragma unroll
    for (int j = 0; j < 8; j++) acc[j] = (f32x4){0.f, 0.f, 0.f, 0.f};

    const float scale = 0.044194173824159216f;   // 512^-0.5
    const float grs = 0.17677669529663687f;      // 32^-0.5

    for (int s = 0; s < nst; s++) {
        int half = s & 1;
        #pragma unroll
        for (int u = 0; u < 4; u++) {
            int idx = u * 256 + t;
            int row = idx >> 6, c = idx & 63;
            *(int4*)&Ks[row * 512 + (c ^ (row & 7)) * 8] = kpre[u];
            int vkv = (idx >> 2) & 15, vdc = (idx & 3) | ((idx >> 6) << 2);
            int kvp = half * 16 + vkv;
            u16 vv[8];
            *(int4*)vv = vpre[u];
            #pragma unroll
            for (int i = 0; i < 8; i++) {
                int d = vdc * 8 + i;
                Vt[d * 32 + (((kvp >> 3) ^ (d & 3)) << 3) + (kvp & 7)] = vv[i];
            }
        }
        __syncthreads();
        if (s + 1 < nst) {
            long rk = rowk0 + (long)(s + 1) * 16;
            #pragma unroll
            for (int u = 0; u < 4; u++) {
                int idx = u * 256 + t;
                kpre[u] = *(const int4*)&k_bf[(rk + (idx >> 6)) * DIMD + (idx & 63) * 8];
                int vkv = (idx >> 2) & 15, vdc = (idx & 3) | ((idx >> 6) << 2);
                vpre[u] = *(const int4*)&v_bf[(rk + vkv) * DIMD + vdc * 8];
            }
        }
        f32x4 sacc = (f32x4){0.f, 0.f, 0.f, 0.f};
        #pragma unroll
        for (int f = 0; f < 4; f++) {
            int cidx = wave * 16 + f * 4 + quad;
            bf16x8 kf = *(const bf16x8*)&Ks[lm * 512 + (cidx ^ (lm & 7)) * 8];
            sacc = __builtin_amdgcn_mfma_f32_16x16x32_bf16(qf[f], kf, sacc, 0, 0, 0);
        }
        #pragma unroll
        for (int r = 0; r < 4; r++) part[wave][quad * 4 + r][lm] = sacc[r];
        if (wave == 3) {
            bf16x8 gkf = *(const bf16x8*)&gk_bf[(rowk0 + (long)s * 16 + lm) * RANK + quad * 8];
            f32x4 gacc = (f32x4){0.f, 0.f, 0.f, 0.f};
            gacc = __builtin_amdgcn_mfma_f32_16x16x32_bf16(gqf, gkf, gacc, 0, 0, 0);
            #pragma unroll
            for (int r = 0; r < 4; r++) Gb[quad * 4 + r][lm] = gacc[r];
        }
        __syncthreads();
        float sv = (part[0][qi][ki] + part[1][qi][ki] + part[2][qi][ki] + part[3][qi][ki]) * scale;
        float gl = Gb[qi][ki] * grs;
        float sig = 1.f / (1.f + expf(-gl));
        sv += logf(sig + 1e-6f);
        float mx = sv;
        mx = fmaxf(mx, __shfl_xor(mx, 1));
        mx = fmaxf(mx, __shfl_xor(mx, 2));
        mx = fmaxf(mx, __shfl_xor(mx, 4));
        mx = fmaxf(mx, __shfl_xor(mx, 8));
        float m_new = fmaxf(m_run, mx);
        float p = expf(sv - m_new);
        float ps = p;
        ps += __shfl_xor(ps, 1);
        ps += __shfl_xor(ps, 2);
        ps += __shfl_xor(ps, 4);
        ps += __shfl_xor(ps, 8);
        float alpha = expf(m_run - m_new);
        l_run = l_run * alpha + ps;
        m_run = m_new;
        Pb[qi * 40 + half * 16 + ki] = f2bf(p);
        if (half == 1) {
            Pb[qi * 40 + ki] = f2bf(bf2f(Pb[qi * 40 + ki]) * alpha);
        }
        bool dopv = (half == 1) || (s == nst - 1);
        if (dopv && half == 0) Pb[qi * 40 + 16 + ki] = 0;
        if (ki == 0) {
            if (half == 0) alphap[qi] = alpha;
            else           alphap[qi] *= alpha;
            if (s == nst - 1) linv[qi] = 1.f / l_run;
        }
        __syncthreads();
        if (dopv) {
            float ar[4];
            #pragma unroll
            for (int r = 0; r < 4; r++) ar[r] = alphap[quad * 4 + r];
            #pragma unroll
            for (int j = 0; j < 8; j++)
                #pragma unroll
                for (int r = 0; r < 4; r++) acc[j][r] *= ar[r];
            bf16x8 pf = *(const bf16x8*)&Pb[lm * 40 + quad * 8];
            #pragma unroll
            for (int j = 0; j < 8; j++) {
                int d = wave * 128 + j * 16 + lm;
                bf16x8 vf = *(const bf16x8*)&Vt[d * 32 + ((quad ^ (d & 3)) << 3)];
                acc[j] = __builtin_amdgcn_mfma_f32_16x16x32_bf16(pf, vf, acc[j], 0, 0, 0);
            }
            __syncthreads();
        }
    }
    float li[4];
    #pragma unroll
    for (int r = 0; r < 4; r++) li[r] = linv[quad * 4 + r];
    #pragma unroll
    for (int j = 0; j < 8; j++) {
        int d = wave * 128 + j * 16 + lm;
        #pragma unroll
        for (int r = 0; r < 4; r++)
            ctx[(rowq0 + quad * 4 + r) * DIMD + d] = f2bf(acc[j][r] * li[r]);
    }
}

// ---------------------------------------------------------------------------
extern "C" void kernel_launch(void* const* d_in, const int* in_sizes, int n_in,
                              void* d_out, int out_size, void* d_ws, size_t ws_size,
                              hipStream_t stream) {
    const float* query  = (const float*)d_in[0];
    const float* source = (const float*)d_in[1];
    const float* ctx0   = (const float*)d_in[2];
    const float* ctx1   = (const float*)d_in[3];
    // d_in[4] = mask: structurally known local window, unused
    const float* qn_g  = (const float*)d_in[5];
    const float* qn_b  = (const float*)d_in[6];
    const float* kvn_g = (const float*)d_in[7];
    const float* kvn_b = (const float*)d_in[8];
    const float* Wq = (const float*)d_in[9];   const float* bq = (const float*)d_in[10];
    const float* Wk = (const float*)d_in[11];  const float* bk = (const float*)d_in[12];
    const float* Wv = (const float*)d_in[13];  const float* bv = (const float*)d_in[14];
    const float* Wo = (const float*)d_in[15];  const float* bo = (const float*)d_in[16];
    const float* Wgq = (const float*)d_in[17];
    const float* Wgk = (const float*)d_in[18];
    const float* Wc0 = (const float*)d_in[19]; const float* bc0 = (const float*)d_in[20];
    const float* Wc1 = (const float*)d_in[21]; const float* bc1 = (const float*)d_in[22];
    const float* Wf  = (const float*)d_in[23]; const float* bfv = (const float*)d_in[24];

    // ---- workspace layout ----
    float* ws = (float*)d_ws;
    float* h      = ws;                         // 4096
    float* gamma  = h + 4096;                   // 4096
    float* beta   = gamma + 4096;               // 4096
    float* biaskv = beta + 4096;                // 1088
    float* biasq  = biaskv + 1088;              // 576
    u16* u = (u16*)(biasq + 576);
    u16* sln  = u;                 u += (long)MK * DIMD;   // LN(source) bf16
    u16* qln  = u;                 u += (long)MQ * DIMD;   // LN+FiLM(query) bf16
    u16* kp   = u;                 u += (long)MK * DIMD;   // k proj bf16
    u16* vp   = u;                 u += (long)MK * DIMD;   // v proj bf16
    u16* gk   = u;                 u += (long)MK * RANK;   // gate_k bf16
    u16* gq   = u;                 u += (long)MQ * RANK;   // gate_q bf16
    u16* qp   = u;                 u += (long)MQ * DIMD;   // q proj bf16
    u16* ctxb = u;                 u += (long)MQ * DIMD;   // attention output bf16
    u16* Btkv = u;                 u += 1152L * DIMD;      // [Wk^T | Wv^T | (Wk·Wgk)^T]
    u16* Btq  = u;                 u += 640L * DIMD;       // [Wq^T | (Wq·Wgq)^T]
    u16* Bto  = u;                 u += 512L * DIMD;       // Wo^T
    float* out = (float*)d_out;

    // FiLM conditioning
    film_h_kernel<<<64, 256, 0, stream>>>(ctx0, ctx1, Wc0, bc0, Wc1, bc1, h);
    film_gb_kernel<<<64, 256, 0, stream>>>(h, Wf, bfv, gamma, beta);

    // Normalized bf16 activations (wave-per-row)
    norm_bf16_kernel<0><<<MK / 4, 256, 0, stream>>>(source, kvn_g, kvn_b, nullptr, nullptr, sln);
    norm_bf16_kernel<1><<<MQ / 4, 256, 0, stream>>>(query, qn_g, qn_b, gamma, beta, qln);

    // Weight prep
    transpose_bf16_kernel<<<dim3(16, 16), 256, 0, stream>>>(Wk, Btkv, 512, 0);
    transpose_bf16_kernel<<<dim3(16, 16), 256, 0, stream>>>(Wv, Btkv, 512, 512);
    gatefuse_kernel<<<64, 256, 0, stream>>>(Wk, Wgk, Btkv, 1024);
    transpose_bf16_kernel<<<dim3(16, 16), 256, 0, stream>>>(Wq, Btq, 512, 0);
    gatefuse_kernel<<<64, 256, 0, stream>>>(Wq, Wgq, Btq, 512);
    transpose_bf16_kernel<<<dim3(16, 16), 256, 0, stream>>>(Wo, Bto, 512, 0);
    biascat3_kernel<<<5, 256, 0, stream>>>(bk, bv, Wgk, biaskv);
    biascat2_kernel<<<3, 256, 0, stream>>>(bq, Wgq, biasq);

    // Projections (bf16 outputs). 1-D grids with XCD swizzle.
    gemm_mfma_kernel<3, true><<<2304, 256, 0, stream>>>(
        sln, Btkv, biaskv, kp, vp, gk, 1056, 9, 32);
    gemm_mfma_kernel<2, true><<<320, 256, 0, stream>>>(
        qln, Btq, biasq, qp, nullptr, gq, 544, 5, 8);

    // Flash local attention
    attn_kernel<<<BATCH * QS, 256, 0, stream>>>(qp, kp, vp, gq, gk, ctxb);

    // Output projection (fp32 out)
    gemm_mfma_kernel<1, false><<<256, 256, 0, stream>>>(
        ctxb, Bto, bo, out, nullptr, nullptr, 512, 4, 8);
}

// Round 5
// 354.842 us; speedup vs baseline: 2.9691x; 1.3491x over previous
//
#include <hip/hip_runtime.h>
#include <math.h>

// Problem constants
#define DIMD 512
#define QS 64
#define KS 256
#define WIN 4
#define BATCH 8
#define RANK 32
#define NQ 1024             // q tokens per batch
#define NK 4096             // kv tokens per batch
#define MQ (BATCH*NQ)       // 8192 q rows
#define MK (BATCH*NK)       // 32768 kv rows

typedef unsigned short u16;
typedef __attribute__((ext_vector_type(8))) short bf16x8;  // MFMA A/B frag (8 bf16)
typedef __attribute__((ext_vector_type(4))) float f32x4;   // MFMA C/D frag

__device__ inline u16 f2bf(float x) {
    union { float f; unsigned int u; } v; v.f = x;
    unsigned int r = v.u + 0x7FFF + ((v.u >> 16) & 1);
    return (u16)(r >> 16);
}
__device__ inline float bf2f(u16 x) {
    union { unsigned int u; float f; } v; v.u = ((unsigned int)x) << 16;
    return v.f;
}

// async global->LDS, 16 B per lane. LDS dest = wave-uniform base + lane*16.
__device__ __forceinline__ void gload16(const u16* g, u16* l) {
    __builtin_amdgcn_global_load_lds(
        (const __attribute__((address_space(1))) void*)g,
        (__attribute__((address_space(3))) void*)l, 16, 0, 0);
}

// ===========================================================================
// Device bodies (verbatim logic from round-4 kernels, blockIdx -> bid param)
// ===========================================================================

// norm (FILM=0): LN(source)*g+b -> bf16, one wave per row, 4 rows/block
__device__ __forceinline__ void norm0_body(
    int bid, const float* __restrict__ X, const float* __restrict__ g,
    const float* __restrict__ bb, u16* __restrict__ out)
{
    int wave = threadIdx.x >> 6, lane = threadIdx.x & 63;
    long row = (long)bid * 4 + wave;
    const float* x = X + row * DIMD;
    int c = lane * 8;
    float4 a = *(const float4*)&x[c];
    float4 b = *(const float4*)&x[c + 4];
    float s  = a.x + a.y + a.z + a.w + b.x + b.y + b.z + b.w;
    float ss = a.x*a.x + a.y*a.y + a.z*a.z + a.w*a.w
             + b.x*b.x + b.y*b.y + b.z*b.z + b.w*b.w;
    #pragma unroll
    for (int o = 1; o < 64; o <<= 1) { s += __shfl_xor(s, o); ss += __shfl_xor(ss, o); }
    float mu = s * (1.f / DIMD);
    float var = ss * (1.f / DIMD) - mu * mu;
    float rs = rsqrtf(var + 1e-5f);
    float4 g0 = *(const float4*)&g[c],  g1 = *(const float4*)&g[c + 4];
    float4 b0 = *(const float4*)&bb[c], b1 = *(const float4*)&bb[c + 4];
    u16 o8[8];
    o8[0] = f2bf((a.x - mu) * rs * g0.x + b0.x);
    o8[1] = f2bf((a.y - mu) * rs * g0.y + b0.y);
    o8[2] = f2bf((a.z - mu) * rs * g0.z + b0.z);
    o8[3] = f2bf((a.w - mu) * rs * g0.w + b0.w);
    o8[4] = f2bf((b.x - mu) * rs * g1.x + b1.x);
    o8[5] = f2bf((b.y - mu) * rs * g1.y + b1.y);
    o8[6] = f2bf((b.z - mu) * rs * g1.z + b1.z);
    o8[7] = f2bf((b.w - mu) * rs * g1.w + b1.w);
    *(int4*)&out[row * DIMD + c] = *(const int4*)o8;
}

// row stats for query rows: mu, rstd. One wave per row, 4 rows/block.
__device__ __forceinline__ void stats_body(
    int bid, const float* __restrict__ X, float* __restrict__ mu_o, float* __restrict__ rs_o)
{
    int wave = threadIdx.x >> 6, lane = threadIdx.x & 63;
    long row = (long)bid * 4 + wave;
    const float* x = X + row * DIMD;
    int c = lane * 8;
    float4 a = *(const float4*)&x[c];
    float4 b = *(const float4*)&x[c + 4];
    float s  = a.x + a.y + a.z + a.w + b.x + b.y + b.z + b.w;
    float ss = a.x*a.x + a.y*a.y + a.z*a.z + a.w*a.w
             + b.x*b.x + b.y*b.y + b.z*b.z + b.w*b.w;
    #pragma unroll
    for (int o = 1; o < 64; o <<= 1) { s += __shfl_xor(s, o); ss += __shfl_xor(ss, o); }
    if (lane == 0) {
        float mu = s * (1.f / DIMD);
        float var = ss * (1.f / DIMD) - mu * mu;
        mu_o[row] = mu;
        rs_o[row] = rsqrtf(var + 1e-5f);
    }
}

// film_h: h = silu(ctx0@Wc0 + bc0 + ctx1@Wc1 + bc1), bid in [0,64)
__device__ __forceinline__ void film_h_body(
    int bid, const float* __restrict__ ctx0, const float* __restrict__ ctx1,
    const float* __restrict__ Wc0, const float* __restrict__ bc0,
    const float* __restrict__ Wc1, const float* __restrict__ bc1,
    float* __restrict__ h)
{
    int b = bid >> 3;
    int d0 = (bid & 7) * 64;
    int t = threadIdx.x;
    int dl = t >> 2, p = t & 3;
    int d = d0 + dl;
    const float* c0 = ctx0 + b * DIMD;
    const float* c1 = ctx1 + b * DIMD;
    float acc = 0.f;
    #pragma unroll 4
    for (int ii = 0; ii < 128; ii++) {
        int i = p * 128 + ii;
        acc = fmaf(c0[i], Wc0[i * DIMD + d], acc);
        acc = fmaf(c1[i], Wc1[i * DIMD + d], acc);
    }
    acc += __shfl_xor(acc, 1);
    acc += __shfl_xor(acc, 2);
    if (p == 0) {
        float v = acc + bc0[d] + bc1[d];
        h[b * DIMD + d] = v / (1.f + expf(-v));
    }
}

// film_gb: gamma,beta = split(h @ Wf + bf), bid in [0,64)
__device__ __forceinline__ void film_gb_body(
    int bid, const float* __restrict__ h, const float* __restrict__ Wf,
    const float* __restrict__ bfv, float* __restrict__ gamma, float* __restrict__ beta)
{
    int b = bid >> 3;
    int d0 = (bid & 7) * 64;
    int t = threadIdx.x;
    int dl = t >> 2, p = t & 3;
    int d = d0 + dl;
    const float* hb = h + b * DIMD;
    float ga = 0.f, be = 0.f;
    #pragma unroll 4
    for (int ii = 0; ii < 128; ii++) {
        int i = p * 128 + ii;
        float hv = hb[i];
        ga = fmaf(hv, Wf[i * 2 * DIMD + d], ga);
        be = fmaf(hv, Wf[i * 2 * DIMD + DIMD + d], be);
    }
    ga += __shfl_xor(ga, 1); ga += __shfl_xor(ga, 2);
    be += __shfl_xor(be, 1); be += __shfl_xor(be, 2);
    if (p == 0) {
        gamma[b * DIMD + d] = ga + bfv[d];
        beta[b * DIMD + d]  = be + bfv[DIMD + d];
    }
}

// transpose W[512][512] -> bf16 dst[dst_row_off + n][k], i in [0,256)
__device__ __forceinline__ void transpose_body(
    int i, const float* __restrict__ src, u16* __restrict__ dst, int dst_row_off,
    float (*tile)[33])
{
    int t = threadIdx.x;
    int tx = t & 31, ty = t >> 5;
    int bx = (i & 15) * 32;
    int by = (i >> 4) * 32;
    #pragma unroll
    for (int k = 0; k < 4; k++)
        tile[ty + k * 8][tx] = src[(long)(by + ty + k * 8) * DIMD + bx + tx];
    __syncthreads();
    #pragma unroll
    for (int k = 0; k < 4; k++)
        dst[(long)(dst_row_off + bx + ty + k * 8) * DIMD + by + tx] = f2bf(tile[tx][ty + k * 8]);
}

// gatefuse: dst[off+r][k] = sum_j W[k][j]*Wg[j][r], idx = global elem id
__device__ __forceinline__ void gatefuse_body(
    int idx, const float* __restrict__ W, const float* __restrict__ Wg,
    u16* __restrict__ dst, int dst_row_off)
{
    int r = idx & 31, k = idx >> 5;
    float acc = 0.f;
    #pragma unroll 4
    for (int j = 0; j < DIMD; j++) acc = fmaf(W[k * DIMD + j], Wg[j * RANK + r], acc);
    dst[(long)(dst_row_off + r) * DIMD + k] = f2bf(acc);
}

__device__ __forceinline__ void biascat3_body(
    int bid, const float* __restrict__ b0, const float* __restrict__ b1,
    const float* __restrict__ Wg, float* __restrict__ dst)
{
    int t = bid * 256 + threadIdx.x;
    if (t < 512) dst[t] = b0[t];
    else if (t < 1024) dst[t] = b1[t - 512];
    else if (t < 1056) {
        int r = t - 1024;
        float a = 0.f;
        for (int j = 0; j < DIMD; j++) a = fmaf(b0[j], Wg[j * RANK + r], a);
        dst[t] = a;
    }
}

__device__ __forceinline__ void biascat2_body(
    int bid, const float* __restrict__ b0, const float* __restrict__ Wg,
    float* __restrict__ dst)
{
    int t = bid * 256 + threadIdx.x;
    if (t < 512) dst[t] = b0[t];
    else if (t < 544) {
        int r = t - 512;
        float a = 0.f;
        for (int j = 0; j < DIMD; j++) a = fmaf(b0[j], Wg[j * RANK + r], a);
        dst[t] = a;
    }
}

// ---------------------------------------------------------------------------
// bf16 MFMA GEMM body (m97 structure), id = logical block index
// ---------------------------------------------------------------------------
template<int NSEC, bool BF>
__device__ __forceinline__ void gemm_body(
    int id, const u16* __restrict__ A, const u16* __restrict__ Bt,
    const float* __restrict__ biascat,
    void* __restrict__ C0v, void* __restrict__ C1v, void* __restrict__ Cgv,
    int Nvalid, int nx, int ypg, u16* smem)
{
    u16* As = smem;
    u16* Bs = smem + 4096;

    int t = threadIdx.x;
    int wave = t >> 6, lane = t & 63;
    int xcd = id & 7, li = id >> 3;
    int by = xcd * ypg + li / nx;
    int bx = li % nx;
    int m0 = by * 128, n0 = bx * 128;
    int mhalf = (wave >> 1) * 64, nhalf = (wave & 1) * 64;
    int lm = lane & 15, quad = lane >> 4;

    int srow = wave * 32 + (lane >> 2);
    int scol = (lane & 3) * 8;
    const u16* Ag = A + (long)(m0 + srow) * DIMD + scol;
    const u16* Bg = Bt + (long)(n0 + srow) * DIMD + scol;
    u16* Asl = As + wave * 1024 + lane * 8;
    u16* Bsl = Bs + wave * 1024 + lane * 8;

    f32x4 acc[4][4];
    #pragma unroll
    for (int i = 0; i < 4; i++)
        #pragma unroll
        for (int j = 0; j < 4; j++)
            acc[i][j] = (f32x4){0.f, 0.f, 0.f, 0.f};

    for (int k0 = 0; k0 < DIMD; k0 += 32) {
        __syncthreads();
        gload16(Ag + k0, Asl);
        gload16(Ag + 16 * DIMD + k0, Asl + 512);
        gload16(Bg + k0, Bsl);
        gload16(Bg + 16 * DIMD + k0, Bsl + 512);
        __syncthreads();
        bf16x8 af[4], bfr[4];
        #pragma unroll
        for (int i = 0; i < 4; i++) {
            af[i]  = *(const bf16x8*)&As[(mhalf + i * 16 + lm) * 32 + quad * 8];
            bfr[i] = *(const bf16x8*)&Bs[(nhalf + i * 16 + lm) * 32 + quad * 8];
        }
        #pragma unroll
        for (int i = 0; i < 4; i++)
            #pragma unroll
            for (int j = 0; j < 4; j++)
                acc[i][j] = __builtin_amdgcn_mfma_f32_16x16x32_bf16(af[i], bfr[j], acc[i][j], 0, 0, 0);
    }

    float biasj[4];
    #pragma unroll
    for (int j = 0; j < 4; j++) biasj[j] = biascat[n0 + nhalf + j * 16 + lm];

    if (BF) {
        for (int i = 0; i < 4; i++) {
            __syncthreads();
            #pragma unroll
            for (int j = 0; j < 4; j++)
                #pragma unroll
                for (int r = 0; r < 4; r++)
                    smem[((wave >> 1) * 16 + quad * 4 + r) * 128 + nhalf + j * 16 + lm] =
                        f2bf(acc[i][j][r] + biasj[j]);
            __syncthreads();
            #pragma unroll
            for (int u = 0; u < 2; u++) {
                int cch = t + u * 256;
                int R = cch >> 4, ci = cch & 15;
                long grow = m0 + (R >> 4) * 64 + i * 16 + (R & 15);
                int gcol = n0 + ci * 8;
                int4 val = *(const int4*)&smem[R * 128 + ci * 8];
                if (NSEC == 1) {
                    *(int4*)((u16*)C0v + grow * 512 + gcol) = val;
                } else if (NSEC == 2) {
                    if (gcol < 512)          *(int4*)((u16*)C0v + grow * 512 + gcol) = val;
                    else if (gcol < Nvalid)  *(int4*)((u16*)Cgv + grow * 32 + (gcol - 512)) = val;
                } else {
                    if (gcol < 512)          *(int4*)((u16*)C0v + grow * 512 + gcol) = val;
                    else if (gcol < 1024)    *(int4*)((u16*)C1v + grow * 512 + (gcol - 512)) = val;
                    else if (gcol < Nvalid)  *(int4*)((u16*)Cgv + grow * 32 + (gcol - 1024)) = val;
                }
            }
        }
    } else {
        float* Stg = (float*)smem;
        for (int i = 0; i < 4; i++) {
            __syncthreads();
            #pragma unroll
            for (int j = 0; j < 4; j++)
                #pragma unroll
                for (int r = 0; r < 4; r++)
                    Stg[((wave >> 1) * 16 + quad * 4 + r) * 128 + nhalf + j * 16 + lm] =
                        acc[i][j][r] + biasj[j];
            __syncthreads();
            #pragma unroll
            for (int u = 0; u < 4; u++) {
                int cch = t + u * 256;
                int R = cch >> 5, ci = cch & 31;
                long grow = m0 + (R >> 4) * 64 + i * 16 + (R & 15);
                int gcol = n0 + ci * 4;
                *(float4*)((float*)C0v + grow * 512 + gcol) = *(const float4*)&Stg[R * 128 + ci * 4];
            }
        }
    }
}

// ===========================================================================
// K1: prep — norm0 | q stats | film_h | transposes | gatefuse | biascat
// ===========================================================================
#define PREP_NORM0   8192
#define PREP_STATS   (PREP_NORM0 + 2048)     // 10240
#define PREP_TRANS   (PREP_STATS + 1024)     // 11264
#define PREP_FILMH   (PREP_TRANS + 64)       // 11328
#define PREP_GATE    (PREP_FILMH + 128)      // 11456
#define PREP_TOTAL   (PREP_GATE + 8)         // 11464

__global__ __launch_bounds__(256) void prep_kernel(
    const float* __restrict__ source, const float* __restrict__ kvn_g,
    const float* __restrict__ kvn_b, u16* __restrict__ sln,
    const float* __restrict__ query, float* __restrict__ mu_q, float* __restrict__ rs_q,
    const float* __restrict__ ctx0, const float* __restrict__ ctx1,
    const float* __restrict__ Wc0, const float* __restrict__ bc0,
    const float* __restrict__ Wc1, const float* __restrict__ bc1,
    float* __restrict__ h,
    const float* __restrict__ Wk, const float* __restrict__ Wv,
    const float* __restrict__ Wq, const float* __restrict__ Wo,
    u16* __restrict__ Btkv, u16* __restrict__ Btq, u16* __restrict__ Bto,
    const float* __restrict__ Wgk, const float* __restrict__ Wgq,
    const float* __restrict__ bk, const float* __restrict__ bv,
    const float* __restrict__ bq, float* __restrict__ biaskv,
    float* __restrict__ biasq)
{
    __shared__ float tile[32][33];
    int bid = blockIdx.x;
    if (bid < PREP_NORM0) {
        norm0_body(bid, source, kvn_g, kvn_b, sln);
    } else if (bid < PREP_STATS) {
        stats_body(bid - PREP_NORM0, query, mu_q, rs_q);
    } else if (bid < PREP_TRANS) {
        int tid = bid - PREP_STATS;
        int which = tid >> 8, i = tid & 255;
        if (which == 0)      transpose_body(i, Wk, Btkv, 0, tile);
        else if (which == 1) transpose_body(i, Wv, Btkv, 512, tile);
        else if (which == 2) transpose_body(i, Wq, Btq, 0, tile);
        else                 transpose_body(i, Wo, Bto, 0, tile);
    } else if (bid < PREP_FILMH) {
        film_h_body(bid - PREP_TRANS, ctx0, ctx1, Wc0, bc0, Wc1, bc1, h);
    } else if (bid < PREP_GATE) {
        int gid = bid - PREP_FILMH;
        int idx = (gid & 63) * 256 + threadIdx.x;
        if (gid < 64) gatefuse_body(idx, Wk, Wgk, Btkv, 1024);
        else          gatefuse_body(idx, Wq, Wgq, Btq, 512);
    } else {
        int cid = bid - PREP_GATE;
        if (cid < 5) biascat3_body(cid, bk, bv, Wgk, biaskv);
        else         biascat2_body(cid - 5, bq, Wgq, biasq);
    }
}

// ===========================================================================
// K2: film_gb (64 blocks) + kv projection GEMM (2304 blocks)
// ===========================================================================
__global__ __launch_bounds__(256) void kv_kernel(
    const float* __restrict__ h, const float* __restrict__ Wf,
    const float* __restrict__ bfv, float* __restrict__ gamma, float* __restrict__ beta,
    const u16* __restrict__ sln, const u16* __restrict__ Btkv,
    const float* __restrict__ biaskv,
    u16* __restrict__ kp, u16* __restrict__ vp, u16* __restrict__ gk)
{
    __shared__ u16 smem[8192];
    int bid = blockIdx.x;
    if (bid < 64) {
        film_gb_body(bid, h, Wf, bfv, gamma, beta);
    } else {
        gemm_body<3, true>(bid - 64, sln, Btkv, biaskv, kp, vp, gk, 1056, 9, 32, smem);
    }
}

// ===========================================================================
// K3: q projection GEMM with LN+FiLM fused into A-staging
// ===========================================================================
__global__ __launch_bounds__(256) void qproj_kernel(
    const float* __restrict__ query, const float* __restrict__ mu_q,
    const float* __restrict__ rs_q, const float* __restrict__ qn_g,
    const float* __restrict__ qn_b, const float* __restrict__ gamma,
    const float* __restrict__ beta, const u16* __restrict__ Btq,
    const float* __restrict__ biasq, u16* __restrict__ qp, u16* __restrict__ gq)
{
    __shared__ u16 smem[8192];
    u16* As = smem;
    u16* Bs = smem + 4096;

    int t = threadIdx.x;
    int wave = t >> 6, lane = t & 63;
    int id = blockIdx.x;
    int xcd = id & 7, li = id >> 3;
    int by = xcd * 8 + li / 5;
    int bx = li % 5;
    int m0 = by * 128, n0 = bx * 128;
    int mhalf = (wave >> 1) * 64, nhalf = (wave & 1) * 64;
    int lm = lane & 15, quad = lane >> 4;
    int bt = m0 >> 10;                    // batch (128 | 1024, uniform per block)

    int srow = wave * 32 + (lane >> 2);
    int scol = (lane & 3) * 8;
    const u16* Bg = Btq + (long)(n0 + srow) * DIMD + scol;
    u16* Bsl = Bs + wave * 1024 + lane * 8;

    f32x4 acc[4][4];
    #pragma unroll
    for (int i = 0; i < 4; i++)
        #pragma unroll
        for (int j = 0; j < 4; j++)
            acc[i][j] = (f32x4){0.f, 0.f, 0.f, 0.f};

    for (int k0 = 0; k0 < DIMD; k0 += 32) {
        __syncthreads();
        gload16(Bg + k0, Bsl);
        gload16(Bg + 16 * DIMD + k0, Bsl + 512);
        // A staging: LN+FiLM inline, 2 chunks of 8 elements per thread
        #pragma unroll
        for (int u = 0; u < 2; u++) {
            int idx = t + u * 256;            // 0..511
            int r = idx >> 2;                 // row 0..127
            int c8 = (idx & 3) * 8;           // col 0,8,16,24
            long grow = m0 + r;
            int col = k0 + c8;
            const float* xp = &query[grow * DIMD + col];
            float4 x0 = *(const float4*)xp, x1 = *(const float4*)(xp + 4);
            float mu = mu_q[grow], rs = rs_q[grow];
            float4 g0 = *(const float4*)&qn_g[col], g1 = *(const float4*)&qn_g[col + 4];
            float4 b0 = *(const float4*)&qn_b[col], b1 = *(const float4*)&qn_b[col + 4];
            const float* gp = gamma + bt * DIMD + col;
            const float* bp = beta + bt * DIMD + col;
            float4 gm0 = *(const float4*)gp, gm1 = *(const float4*)(gp + 4);
            float4 be0 = *(const float4*)bp, be1 = *(const float4*)(bp + 4);
            u16 o8[8];
            o8[0] = f2bf(((x0.x - mu) * rs * g0.x + b0.x) * (1.f + gm0.x) + be0.x);
            o8[1] = f2bf(((x0.y - mu) * rs * g0.y + b0.y) * (1.f + gm0.y) + be0.y);
            o8[2] = f2bf(((x0.z - mu) * rs * g0.z + b0.z) * (1.f + gm0.z) + be0.z);
            o8[3] = f2bf(((x0.w - mu) * rs * g0.w + b0.w) * (1.f + gm0.w) + be0.w);
            o8[4] = f2bf(((x1.x - mu) * rs * g1.x + b1.x) * (1.f + gm1.x) + be1.x);
            o8[5] = f2bf(((x1.y - mu) * rs * g1.y + b1.y) * (1.f + gm1.y) + be1.y);
            o8[6] = f2bf(((x1.z - mu) * rs * g1.z + b1.z) * (1.f + gm1.z) + be1.z);
            o8[7] = f2bf(((x1.w - mu) * rs * g1.w + b1.w) * (1.f + gm1.w) + be1.w);
            *(int4*)&As[r * 32 + c8] = *(const int4*)o8;
        }
        __syncthreads();
        bf16x8 af[4], bfr[4];
        #pragma unroll
        for (int i = 0; i < 4; i++) {
            af[i]  = *(const bf16x8*)&As[(mhalf + i * 16 + lm) * 32 + quad * 8];
            bfr[i] = *(const bf16x8*)&Bs[(nhalf + i * 16 + lm) * 32 + quad * 8];
        }
        #pragma unroll
        for (int i = 0; i < 4; i++)
            #pragma unroll
            for (int j = 0; j < 4; j++)
                acc[i][j] = __builtin_amdgcn_mfma_f32_16x16x32_bf16(af[i], bfr[j], acc[i][j], 0, 0, 0);
    }

    float biasj[4];
    #pragma unroll
    for (int j = 0; j < 4; j++) biasj[j] = biasq[n0 + nhalf + j * 16 + lm];

    for (int i = 0; i < 4; i++) {
        __syncthreads();
        #pragma unroll
        for (int j = 0; j < 4; j++)
            #pragma unroll
            for (int r = 0; r < 4; r++)
                smem[((wave >> 1) * 16 + quad * 4 + r) * 128 + nhalf + j * 16 + lm] =
                    f2bf(acc[i][j][r] + biasj[j]);
        __syncthreads();
        #pragma unroll
        for (int u = 0; u < 2; u++) {
            int cch = t + u * 256;
            int R = cch >> 4, ci = cch & 15;
            long grow = m0 + (R >> 4) * 64 + i * 16 + (R & 15);
            int gcol = n0 + ci * 8;
            int4 val = *(const int4*)&smem[R * 128 + ci * 8];
            if (gcol < 512)       *(int4*)(qp + grow * 512 + gcol) = val;
            else if (gcol < 544)  *(int4*)(gq + grow * 32 + (gcol - 512)) = val;
        }
    }
}

// ===========================================================================
// K5: output projection (fp32 out)
// ===========================================================================
__global__ __launch_bounds__(256) void ogemm_kernel(
    const u16* __restrict__ ctxb, const u16* __restrict__ Bto,
    const float* __restrict__ bo, float* __restrict__ out)
{
    __shared__ u16 smem[8192];
    gemm_body<1, false>(blockIdx.x, ctxb, Bto, bo, out, nullptr, nullptr, 512, 4, 8, smem);
}

// ===========================================================================
// K4: Flash-style local attention (unchanged from round 3/4)
// ===========================================================================
__global__ __launch_bounds__(256, 2) void attn_kernel(
    const u16* __restrict__ q_bf, const u16* __restrict__ k_bf,
    const u16* __restrict__ v_bf, const u16* __restrict__ gq_bf,
    const u16* __restrict__ gk_bf, u16* __restrict__ ctx)
{
    __shared__ u16 Ks[16 * 512];
    __shared__ u16 Vt[512 * 32];
    __shared__ u16 Pb[16 * 40];
    __shared__ float part[4][16][16];
    __shared__ float Gb[16][16];
    __shared__ float alphap[16];
    __shared__ float linv[16];

    int blk = blockIdx.x;
    int b = blk >> 6, qs = blk & 63;
    int center = (int)(qs * (255.0f / 63.0f) + 0.5f);
    int lo = center - WIN; if (lo < 0) lo = 0;
    int hi = center + WIN; if (hi > KS - 1) hi = KS - 1;
    int nst = hi - lo + 1;
    long rowq0 = (long)b * NQ + qs * 16;
    long rowk0 = (long)b * NK + lo * 16;

    int t = threadIdx.x;
    int wave = t >> 6, lane = t & 63;
    int lm = lane & 15, quad = lane >> 4;
    int qi = t >> 4, ki = t & 15;

    bf16x8 qf[4];
    #pragma unroll
    for (int f = 0; f < 4; f++)
        qf[f] = *(const bf16x8*)&q_bf[(rowq0 + lm) * DIMD + wave * 128 + f * 32 + quad * 8];
    bf16x8 gqf;
    if (wave == 3) gqf = *(const bf16x8*)&gq_bf[(rowq0 + lm) * RANK + quad * 8];

    int4 kpre[4], vpre[4];
    #pragma unroll
    for (int u = 0; u < 4; u++) {
        int idx = u * 256 + t;
        kpre[u] = *(const int4*)&k_bf[(rowk0 + (idx >> 6)) * DIMD + (idx & 63) * 8];
        int vkv = (idx >> 2) & 15, vdc = (idx & 3) | ((idx >> 6) << 2);
        vpre[u] = *(const int4*)&v_bf[(rowk0 + vkv) * DIMD + vdc * 8];
    }

    float m_run = -1e30f, l_run = 0.f;
    f32x4 acc[8];
    #pragma unroll
    for (int j = 0; j < 8; j++) acc[j] = (f32x4){0.f, 0.f, 0.f, 0.f};

    const float scale = 0.044194173824159216f;   // 512^-0.5
    const float grs = 0.17677669529663687f;      // 32^-0.5

    for (int s = 0; s < nst; s++) {
        int half = s & 1;
        #pragma unroll
        for (int u = 0; u < 4; u++) {
            int idx = u * 256 + t;
            int row = idx >> 6, c = idx & 63;
            *(int4*)&Ks[row * 512 + (c ^ (row & 7)) * 8] = kpre[u];
            int vkv = (idx >> 2) & 15, vdc = (idx & 3) | ((idx >> 6) << 2);
            int kvp = half * 16 + vkv;
            u16 vv[8];
            *(int4*)vv = vpre[u];
            #pragma unroll
            for (int i = 0; i < 8; i++) {
                int d = vdc * 8 + i;
                Vt[d * 32 + (((kvp >> 3) ^ (d & 3)) << 3) + (kvp & 7)] = vv[i];
            }
        }
        __syncthreads();
        if (s + 1 < nst) {
            long rk = rowk0 + (long)(s + 1) * 16;
            #pragma unroll
            for (int u = 0; u < 4; u++) {
                int idx = u * 256 + t;
                kpre[u] = *(const int4*)&k_bf[(rk + (idx >> 6)) * DIMD + (idx & 63) * 8];
                int vkv = (idx >> 2) & 15, vdc = (idx & 3) | ((idx >> 6) << 2);
                vpre[u] = *(const int4*)&v_bf[(rk + vkv) * DIMD + vdc * 8];
            }
        }
        f32x4 sacc = (f32x4){0.f, 0.f, 0.f, 0.f};
        #pragma unroll
        for (int f = 0; f < 4; f++) {
            int cidx = wave * 16 + f * 4 + quad;
            bf16x8 kf = *(const bf16x8*)&Ks[lm * 512 + (cidx ^ (lm & 7)) * 8];
            sacc = __builtin_amdgcn_mfma_f32_16x16x32_bf16(qf[f], kf, sacc, 0, 0, 0);
        }
        #pragma unroll
        for (int r = 0; r < 4; r++) part[wave][quad * 4 + r][lm] = sacc[r];
        if (wave == 3) {
            bf16x8 gkf = *(const bf16x8*)&gk_bf[(rowk0 + (long)s * 16 + lm) * RANK + quad * 8];
            f32x4 gacc = (f32x4){0.f, 0.f, 0.f, 0.f};
            gacc = __builtin_amdgcn_mfma_f32_16x16x32_bf16(gqf, gkf, gacc, 0, 0, 0);
            #pragma unroll
            for (int r = 0; r < 4; r++) Gb[quad * 4 + r][lm] = gacc[r];
        }
        __syncthreads();
        float sv = (part[0][qi][ki] + part[1][qi][ki] + part[2][qi][ki] + part[3][qi][ki]) * scale;
        float gl = Gb[qi][ki] * grs;
        float sig = 1.f / (1.f + expf(-gl));
        sv += logf(sig + 1e-6f);
        float mx = sv;
        mx = fmaxf(mx, __shfl_xor(mx, 1));
        mx = fmaxf(mx, __shfl_xor(mx, 2));
        mx = fmaxf(mx, __shfl_xor(mx, 4));
        mx = fmaxf(mx, __shfl_xor(mx, 8));
        float m_new = fmaxf(m_run, mx);
        float p = expf(sv - m_new);
        float ps = p;
        ps += __shfl_xor(ps, 1);
        ps += __shfl_xor(ps, 2);
        ps += __shfl_xor(ps, 4);
        ps += __shfl_xor(ps, 8);
        float alpha = expf(m_run - m_new);
        l_run = l_run * alpha + ps;
        m_run = m_new;
        Pb[qi * 40 + half * 16 + ki] = f2bf(p);
        if (half == 1) {
            Pb[qi * 40 + ki] = f2bf(bf2f(Pb[qi * 40 + ki]) * alpha);
        }
        bool dopv = (half == 1) || (s == nst - 1);
        if (dopv && half == 0) Pb[qi * 40 + 16 + ki] = 0;
        if (ki == 0) {
            if (half == 0) alphap[qi] = alpha;
            else           alphap[qi] *= alpha;
            if (s == nst - 1) linv[qi] = 1.f / l_run;
        }
        __syncthreads();
        if (dopv) {
            float ar[4];
            #pragma unroll
            for (int r = 0; r < 4; r++) ar[r] = alphap[quad * 4 + r];
            #pragma unroll
            for (int j = 0; j < 8; j++)
                #pragma unroll
                for (int r = 0; r < 4; r++) acc[j][r] *= ar[r];
            bf16x8 pf = *(const bf16x8*)&Pb[lm * 40 + quad * 8];
            #pragma unroll
            for (int j = 0; j < 8; j++) {
                int d = wave * 128 + j * 16 + lm;
                bf16x8 vf = *(const bf16x8*)&Vt[d * 32 + ((quad ^ (d & 3)) << 3)];
                acc[j] = __builtin_amdgcn_mfma_f32_16x16x32_bf16(pf, vf, acc[j], 0, 0, 0);
            }
            __syncthreads();
        }
    }
    float li[4];
    #pragma unroll
    for (int r = 0; r < 4; r++) li[r] = linv[quad * 4 + r];
    #pragma unroll
    for (int j = 0; j < 8; j++) {
        int d = wave * 128 + j * 16 + lm;
        #pragma unroll
        for (int r = 0; r < 4; r++)
            ctx[(rowq0 + quad * 4 + r) * DIMD + d] = f2bf(acc[j][r] * li[r]);
    }
}

// ---------------------------------------------------------------------------
extern "C" void kernel_launch(void* const* d_in, const int* in_sizes, int n_in,
                              void* d_out, int out_size, void* d_ws, size_t ws_size,
                              hipStream_t stream) {
    const float* query  = (const float*)d_in[0];
    const float* source = (const float*)d_in[1];
    const float* ctx0   = (const float*)d_in[2];
    const float* ctx1   = (const float*)d_in[3];
    // d_in[4] = mask: structurally known local window, unused
    const float* qn_g  = (const float*)d_in[5];
    const float* qn_b  = (const float*)d_in[6];
    const float* kvn_g = (const float*)d_in[7];
    const float* kvn_b = (const float*)d_in[8];
    const float* Wq = (const float*)d_in[9];   const float* bq = (const float*)d_in[10];
    const float* Wk = (const float*)d_in[11];  const float* bk = (const float*)d_in[12];
    const float* Wv = (const float*)d_in[13];  const float* bv = (const float*)d_in[14];
    const float* Wo = (const float*)d_in[15];  const float* bo = (const float*)d_in[16];
    const float* Wgq = (const float*)d_in[17];
    const float* Wgk = (const float*)d_in[18];
    const float* Wc0 = (const float*)d_in[19]; const float* bc0 = (const float*)d_in[20];
    const float* Wc1 = (const float*)d_in[21]; const float* bc1 = (const float*)d_in[22];
    const float* Wf  = (const float*)d_in[23]; const float* bfv = (const float*)d_in[24];

    // ---- workspace layout ----
    float* ws = (float*)d_ws;
    float* h      = ws;                         // 4096
    float* gamma  = h + 4096;                   // 4096
    float* beta   = gamma + 4096;               // 4096
    float* biaskv = beta + 4096;                // 1152
    float* biasq  = biaskv + 1152;              // 640
    float* mu_q   = biasq + 640;                // 8192
    float* rs_q   = mu_q + 8192;                // 8192
    u16* u = (u16*)(rs_q + 8192);
    u16* sln  = u;                 u += (long)MK * DIMD;   // LN(source) bf16
    u16* kp   = u;                 u += (long)MK * DIMD;   // k proj bf16
    u16* vp   = u;                 u += (long)MK * DIMD;   // v proj bf16
    u16* gk   = u;                 u += (long)MK * RANK;   // gate_k bf16
    u16* gq   = u;                 u += (long)MQ * RANK;   // gate_q bf16
    u16* qp   = u;                 u += (long)MQ * DIMD;   // q proj bf16
    u16* ctxb = u;                 u += (long)MQ * DIMD;   // attention output bf16
    u16* Btkv = u;                 u += 1152L * DIMD;      // [Wk^T | Wv^T | (Wk·Wgk)^T]
    u16* Btq  = u;                 u += 640L * DIMD;       // [Wq^T | (Wq·Wgq)^T]
    u16* Bto  = u;                 u += 512L * DIMD;       // Wo^T
    float* out = (float*)d_out;

    // K1: everything independent (norm0, q stats, film_h, weight prep)
    prep_kernel<<<PREP_TOTAL, 256, 0, stream>>>(
        source, kvn_g, kvn_b, sln,
        query, mu_q, rs_q,
        ctx0, ctx1, Wc0, bc0, Wc1, bc1, h,
        Wk, Wv, Wq, Wo, Btkv, Btq, Bto,
        Wgk, Wgq, bk, bv, bq, biaskv, biasq);

    // K2: film_gb + kv projection GEMM
    kv_kernel<<<64 + 2304, 256, 0, stream>>>(
        h, Wf, bfv, gamma, beta, sln, Btkv, biaskv, kp, vp, gk);

    // K3: q projection GEMM (LN+FiLM inline)
    qproj_kernel<<<320, 256, 0, stream>>>(
        query, mu_q, rs_q, qn_g, qn_b, gamma, beta, Btq, biasq, qp, gq);

    // K4: flash local attention
    attn_kernel<<<BATCH * QS, 256, 0, stream>>>(qp, kp, vp, gq, gk, ctxb);

    // K5: output projection (fp32 out)
    ogemm_kernel<<<256, 256, 0, stream>>>(ctxb, Bto, bo, out);
}